// Round 1
// baseline (1670.450 us; speedup 1.0000x reference)
//
#include <hip/hip_runtime.h>
#include <hip/hip_bf16.h>
#include <math.h>

// Problem constants (fixed by setup_inputs)
#define BB    4
#define NTOK  16384
#define CIN   128
#define COUT  256
#define HM    256
#define WM    256
#define NP    65536      // HM*WM original points per batch
#define HD    128
#define WD    128
#define HC    64
#define WC    64
#define NS    4096       // HC*WC
#define EPS   1e-6f
#define BNEPS 1e-5f

// ---------------- workspace layout (floats) ----------------
// zeroed block first (one memset), then non-zeroed scratch
static constexpr size_t SSUM_OFF   = 0;                                   // BB*NP*CIN (raw scatter sums; conv normalizes by cnt on load)
static constexpr size_t CNT_OFF    = SSUM_OFF + (size_t)BB * NP * CIN;    // BB*NP
static constexpr size_t NUM2_OFF   = CNT_OFF + (size_t)BB * NP;           // BB*NS*COUT
static constexpr size_t DEN2_OFF   = NUM2_OFF + (size_t)BB * NS * COUT;   // BB*NS
static constexpr size_t DEN1_OFF   = DEN2_OFF + (size_t)BB * NS;          // BB*NTOK
static constexpr size_t BNSUM_OFF  = DEN1_OFF + (size_t)BB * NTOK;        // 256
static constexpr size_t BNSQ_OFF   = BNSUM_OFF + 256;                     // 256
static constexpr size_t MAXW_OFF   = BNSQ_OFF + 256;                      // 4 (uint bits of positive float max)
static constexpr size_t ZERO_FLOATS = MAXW_OFF + 4;
static constexpr size_t Y_OFF      = (ZERO_FLOATS + 255) & ~(size_t)255;  // BB*HD*WD*COUT
static constexpr size_t AWDT_OFF   = Y_OFF + (size_t)BB * HD * WD * COUT; // BB*NP
static constexpr size_t ABUF_OFF   = AWDT_OFF + (size_t)BB * NP;          // 256
static constexpr size_t BBUF_OFF   = ABUF_OFF + 256;                      // 256
static constexpr size_t CWA_OFF    = BBUF_OFF + 256;                      // 256
static constexpr size_t C0_OFF     = CWA_OFF + 256;                       // 1 (padded to 256)
static constexpr size_t SWT_OFF    = C0_OFF + 256;                        // CIN*COUT  skip_w^T [ci][co]
static constexpr size_t CELL256_OFF = SWT_OFF + (size_t)CIN * COUT;       // BB*NP ints
static constexpr size_t CELL64_OFF  = CELL256_OFF + (size_t)BB * NP;      // BB*NP ints

// ---------------- kernels ----------------

// grid cell indices for both grids (matches jnp.round = RNE via rintf)
__global__ void k_cells(const float* __restrict__ loc, int* __restrict__ cell256,
                        int* __restrict__ cell64) {
    int i = blockIdx.x * 256 + threadIdx.x;   // over BB*NP
    float lx = fminf(fmaxf(loc[2 * (size_t)i], -1.f), 1.f);
    float ly = fminf(fmaxf(loc[2 * (size_t)i + 1], -1.f), 1.f);
    int px = (int)rintf(0.5f * (lx + 1.f) * WM - 0.5f);
    px = min(max(px, 0), WM - 1);
    int py = (int)rintf(0.5f * (ly + 1.f) * HM - 0.5f);
    py = min(max(py, 0), HM - 1);
    cell256[i] = py * WM + px;
    int qx = (int)rintf(0.5f * (lx + 1.f) * WC - 0.5f);
    qx = min(max(qx, 0), WC - 1);
    int qy = (int)rintf(0.5f * (ly + 1.f) * HC - 0.5f);
    qy = min(max(qy, 0), HC - 1);
    cell64[i] = qy * WC + qx;
}

__global__ void k_transpose_skip(const float* __restrict__ sw, float* __restrict__ swt) {
    int i = blockIdx.x * 256 + threadIdx.x;   // over COUT*CIN
    int k = i / CIN, c = i % CIN;
    swt[(size_t)c * COUT + k] = sw[i];
}

// token2map scatter: ssum[b,cell,:] += x[b,idx_agg,:]; cnt[b,cell] += 1
__global__ __launch_bounds__(256) void k_scatter_map(const float* __restrict__ x,
                                                     const int* __restrict__ idx_agg,
                                                     const int* __restrict__ cell256,
                                                     float* __restrict__ ssum,
                                                     float* __restrict__ cnt) {
    int gp = blockIdx.x * 8 + (threadIdx.x >> 5);   // point index over BB*NP
    int lane = threadIdx.x & 31;                    // 32 lanes x float4 = 128 ch
    int b = gp >> 16;
    int cell = cell256[gp];
    int ia = idx_agg[gp];
    float4 v = *(const float4*)(x + ((size_t)b * NTOK + ia) * CIN + lane * 4);
    float* dst = ssum + ((size_t)b * NP + cell) * CIN + lane * 4;
    atomicAdd(dst + 0, v.x);
    atomicAdd(dst + 1, v.y);
    atomicAdd(dst + 2, v.z);
    atomicAdd(dst + 3, v.w);
    if (lane == 0) atomicAdd(cnt + (size_t)b * NP + cell, 1.0f);
}

// 3x3 stride-2 pad-1 conv, fp32. Block = (b, oh, 32-wide ow tile); 256 thr =
// 64 n-groups x 4 p-groups; thread micro-tile 4 cout x 8 pixels (32 acc VGPRs).
// Input row window (65 px x 128 c) staged in LDS, normalized by cnt on load.
__global__ __launch_bounds__(256) void k_conv(const float* __restrict__ xmap,
                                              const float* __restrict__ cnt,
                                              const float* __restrict__ cw,
                                              const float* __restrict__ cb,
                                              float* __restrict__ y) {
    int bz = blockIdx.x;
    int tile = bz & 3;
    int oh = (bz >> 2) & (HD - 1);
    int b = bz >> 9;
    int ow0 = tile * 32;
    int tid = threadIdx.x;
    int nt = tid & 63, pt = tid >> 6;
    int n = nt * 4;
    __shared__ float in_lds[65 * CIN];
    float acc[4][8];
#pragma unroll
    for (int i = 0; i < 4; ++i)
#pragma unroll
        for (int j = 0; j < 8; ++j) acc[i][j] = 0.f;
    int iw0 = 2 * ow0 - 1;
    for (int kh = 0; kh < 3; ++kh) {
        int ih = 2 * oh - 1 + kh;
        __syncthreads();
        if (ih >= 0 && ih < HM) {
            const float* rowb = xmap + ((size_t)b * NP + (size_t)ih * WM) * CIN;
            const float* cntb = cnt + (size_t)b * NP + (size_t)ih * WM;
            for (int idx = tid; idx < 65 * 32; idx += 256) {
                int pix = idx >> 5, c4 = idx & 31;
                int iw = iw0 + pix;
                float4 v = make_float4(0.f, 0.f, 0.f, 0.f);
                if (iw >= 0 && iw < WM) {
                    v = *(const float4*)(rowb + (size_t)iw * CIN + c4 * 4);
                    float inv = 1.0f / (cntb[iw] + EPS);
                    v.x *= inv; v.y *= inv; v.z *= inv; v.w *= inv;
                }
                *(float4*)(in_lds + pix * CIN + c4 * 4) = v;
            }
        } else {
            for (int idx = tid; idx < 65 * 32; idx += 256)
                *(float4*)(in_lds + (idx >> 5) * CIN + (idx & 31) * 4) =
                    make_float4(0.f, 0.f, 0.f, 0.f);
        }
        __syncthreads();
#pragma unroll
        for (int kw = 0; kw < 3; ++kw) {
            const float* wb = cw + ((size_t)(kh * 3 + kw) * CIN) * COUT + n;
#pragma unroll 4
            for (int c = 0; c < CIN; ++c) {
                float4 w4 = *(const float4*)(wb + (size_t)c * COUT);
#pragma unroll
                for (int j = 0; j < 8; ++j) {
                    float a = in_lds[(2 * (pt * 8 + j) + kw) * CIN + c];
                    acc[0][j] = fmaf(a, w4.x, acc[0][j]);
                    acc[1][j] = fmaf(a, w4.y, acc[1][j]);
                    acc[2][j] = fmaf(a, w4.z, acc[2][j]);
                    acc[3][j] = fmaf(a, w4.w, acc[3][j]);
                }
            }
        }
    }
    float4 bias = *(const float4*)(cb + n);
    float* yb = y + (((size_t)b * HD + oh) * WD + ow0) * COUT + n;
#pragma unroll
    for (int j = 0; j < 8; ++j) {
        int p = pt * 8 + j;
        float4 o = make_float4(acc[0][j] + bias.x, acc[1][j] + bias.y,
                               acc[2][j] + bias.z, acc[3][j] + bias.w);
        *(float4*)(yb + (size_t)p * COUT) = o;
    }
}

// map2token: bilinear sample y at each point, atomic scatter to token nums
__global__ __launch_bounds__(256) void k_map2tok(const float* __restrict__ y,
                                                 const float* __restrict__ loc,
                                                 const int* __restrict__ idx_agg,
                                                 const float* __restrict__ aggw,
                                                 float* __restrict__ num,
                                                 float* __restrict__ den1) {
    int k = threadIdx.x;
    int gp0 = blockIdx.x * 4;
    for (int g = 0; g < 4; ++g) {
        int gp = gp0 + g;
        int b = gp >> 16;
        float lx = fminf(fmaxf(loc[2 * (size_t)gp], -1.f), 1.f);
        float ly = fminf(fmaxf(loc[2 * (size_t)gp + 1], -1.f), 1.f);
        float fx = fminf(fmaxf(0.5f * (lx + 1.f) * WD - 0.5f, 0.f), (float)(WD - 1));
        float fy = fminf(fmaxf(0.5f * (ly + 1.f) * HD - 0.5f, 0.f), (float)(HD - 1));
        float x0f = floorf(fx), y0f = floorf(fy);
        float wx = fx - x0f, wy = fy - y0f;
        int x0 = (int)x0f, y0 = (int)y0f;
        int x1 = min(x0 + 1, WD - 1), y1 = min(y0 + 1, HD - 1);
        const float* ybase = y + (size_t)b * (HD * WD * COUT);
        float v00 = ybase[((size_t)y0 * WD + x0) * COUT + k];
        float v01 = ybase[((size_t)y0 * WD + x1) * COUT + k];
        float v10 = ybase[((size_t)y1 * WD + x0) * COUT + k];
        float v11 = ybase[((size_t)y1 * WD + x1) * COUT + k];
        float f = (1.f - wx) * (1.f - wy) * v00 + wx * (1.f - wy) * v01 +
                  (1.f - wx) * wy * v10 + wx * wy * v11;
        float w = aggw[gp];
        int ia = idx_agg[gp];
        atomicAdd(num + ((size_t)b * NTOK + ia) * COUT + k, f * w);
        if (k == 0) atomicAdd(den1 + (size_t)b * NTOK + ia, w);
    }
}

// tok = num/(den1+eps) + x @ skip_w^T   (in place over the num buffer = out_x region)
__global__ __launch_bounds__(256) void k_tok(const float* __restrict__ x,
                                             const float* __restrict__ swt,
                                             const float* __restrict__ den1,
                                             float* __restrict__ tok) {
    int t0 = blockIdx.x * 32;
    int tid = threadIdx.x;
    int nt = tid & 63, pt = tid >> 6;
    int n = nt * 4;
    __shared__ float xs[32 * CIN];
    for (int idx = tid; idx < 32 * 32; idx += 256) {
        int p = idx >> 5, c4 = idx & 31;
        *(float4*)(xs + p * CIN + c4 * 4) =
            *(const float4*)(x + ((size_t)(t0 + p)) * CIN + c4 * 4);
    }
    __syncthreads();
    float acc[4][8];
#pragma unroll
    for (int i = 0; i < 4; ++i)
#pragma unroll
        for (int j = 0; j < 8; ++j) acc[i][j] = 0.f;
#pragma unroll 4
    for (int c = 0; c < CIN; ++c) {
        float4 w4 = *(const float4*)(swt + (size_t)c * COUT + n);
#pragma unroll
        for (int j = 0; j < 8; ++j) {
            float a = xs[(pt * 8 + j) * CIN + c];
            acc[0][j] = fmaf(a, w4.x, acc[0][j]);
            acc[1][j] = fmaf(a, w4.y, acc[1][j]);
            acc[2][j] = fmaf(a, w4.z, acc[2][j]);
            acc[3][j] = fmaf(a, w4.w, acc[3][j]);
        }
    }
#pragma unroll
    for (int j = 0; j < 8; ++j) {
        int tkn = t0 + pt * 8 + j;
        float inv = 1.f / (den1[tkn] + EPS);
        float* pp = tok + (size_t)tkn * COUT + n;
        float4 v = *(float4*)pp;
        v.x = v.x * inv + acc[0][j];
        v.y = v.y * inv + acc[1][j];
        v.z = v.z * inv + acc[2][j];
        v.w = v.w * inv + acc[3][j];
        *(float4*)pp = v;
    }
}

__global__ void k_bnstats(const float* __restrict__ tok, float* __restrict__ bnsum,
                          float* __restrict__ bnsq) {
    int k = threadIdx.x;
    size_t t0 = (size_t)blockIdx.x * 256;
    float s = 0.f, sq = 0.f;
    for (int t = 0; t < 256; ++t) {
        float v = tok[(t0 + t) * COUT + k];
        s += v;
        sq = fmaf(v, v, sq);
    }
    atomicAdd(bnsum + k, s);
    atomicAdd(bnsq + k, sq);
}

// per-channel BN affine: a=gamma/sqrt(var+eps), bb=beta-mu*a; fold conf head
__global__ void k_bnparams(const float* __restrict__ bnsum, const float* __restrict__ bnsq,
                           const float* __restrict__ gamma, const float* __restrict__ beta,
                           const float* __restrict__ confw, const float* __restrict__ confb,
                           float* __restrict__ abuf, float* __restrict__ bbuf,
                           float* __restrict__ cwa, float* __restrict__ c0) {
    int k = threadIdx.x;
    const float cntv = (float)(BB * NTOK);
    float mu = bnsum[k] / cntv;
    float var = bnsq[k] / cntv - mu * mu;
    float a = gamma[k] * rsqrtf(var + BNEPS);
    float bbv = beta[k] - mu * a;
    abuf[k] = a;
    bbuf[k] = bbv;
    float cw = confw[k];
    cwa[k] = a * cw;
    __shared__ float red[256];
    red[k] = bbv * cw;
    __syncthreads();
    for (int s = 128; s > 0; s >>= 1) {
        if (k < s) red[k] += red[k + s];
        __syncthreads();
    }
    if (k == 0) c0[0] = red[0] + confb[0];
}

// conf = tokn @ conf_w^T + conf_b, folded:  dot(tok, cwa) + c0
__global__ void k_conf(const float* __restrict__ tok, const float* __restrict__ cwa,
                       const float* __restrict__ c0v, float* __restrict__ conf_out) {
    int tid = threadIdx.x;
    int tkn = blockIdx.x * 16 + (tid >> 4);
    int kc = (tid & 15) * 16;
    const float* row = tok + (size_t)tkn * COUT + kc;
    float s = 0.f;
#pragma unroll
    for (int i = 0; i < 16; i += 4) {
        float4 v = *(const float4*)(row + i);
        float4 w = *(const float4*)(cwa + kc + i);
        s += v.x * w.x + v.y * w.y + v.z * w.z + v.w * w.w;
    }
    for (int off = 8; off > 0; off >>= 1) s += __shfl_down(s, off, 16);
    if ((tid & 15) == 0) conf_out[tkn] = s + c0v[0];
}

// token_cluster_grid scatter: num2[b,cell,:] += tokn[b,ia,:]*w ; den2 += w
__global__ __launch_bounds__(256) void k_cluster(const float* __restrict__ tok,
                                                 const float* __restrict__ conf,
                                                 const int* __restrict__ idx_agg,
                                                 const int* __restrict__ cell64,
                                                 const float* __restrict__ abuf,
                                                 const float* __restrict__ bbuf,
                                                 float* __restrict__ num2,
                                                 float* __restrict__ den2) {
    int k = threadIdx.x;
    float a = abuf[k], bbv = bbuf[k];
    int gp0 = blockIdx.x * 4;
    for (int g = 0; g < 4; ++g) {
        int gp = gp0 + g;
        int b = gp >> 16;
        int ia = idx_agg[gp];
        int cell = cell64[gp];
        float w = expf(conf[(size_t)b * NTOK + ia]);
        float tv = tok[((size_t)b * NTOK + ia) * COUT + k];
        float f = fmaf(a, tv, bbv);
        atomicAdd(num2 + ((size_t)b * NS + cell) * COUT + k, f * w);
        if (k == 0) atomicAdd(den2 + (size_t)b * NS + cell, w);
    }
}

__global__ void k_xdown(const float* __restrict__ num2, const float* __restrict__ den2,
                        float* __restrict__ xdown) {
    size_t i = (size_t)blockIdx.x * 256 + threadIdx.x;  // float4 index over BB*NS*COUT/4
    float4 v = ((const float4*)num2)[i];
    float inv = 1.f / (den2[i >> 6] + EPS);
    v.x = fmaxf(v.x * inv, 0.f);
    v.y = fmaxf(v.y * inv, 0.f);
    v.z = fmaxf(v.z * inv, 0.f);
    v.w = fmaxf(v.w * inv, 0.f);
    ((float4*)xdown)[i] = v;
}

// agg_weight_down numerator + per-batch max (positive floats -> uint atomicMax)
__global__ void k_awd1(const float* __restrict__ conf, const float* __restrict__ den2,
                       const int* __restrict__ idx_agg, const int* __restrict__ cell64,
                       const float* __restrict__ aggw, float* __restrict__ awdt,
                       float* __restrict__ idx_out_f, unsigned int* __restrict__ maxw) {
    int b = blockIdx.x >> 6;
    int chunk = blockIdx.x & 63;
    int base = b * NP + chunk * 1024;
    float lmax = 0.f;
    for (int t = threadIdx.x; t < 1024; t += 256) {
        int gp = base + t;
        int ia = idx_agg[gp];
        int cell = cell64[gp];
        float w = expf(conf[(size_t)b * NTOK + ia]);
        float wt = w / (den2[(size_t)b * NS + cell] + EPS);
        float tv = aggw[gp] * wt;
        awdt[gp] = tv;
        idx_out_f[gp] = (float)cell;
        lmax = fmaxf(lmax, tv);
    }
    __shared__ float red[256];
    red[threadIdx.x] = lmax;
    __syncthreads();
    for (int s = 128; s > 0; s >>= 1) {
        if (threadIdx.x < s) red[threadIdx.x] = fmaxf(red[threadIdx.x], red[threadIdx.x + s]);
        __syncthreads();
    }
    if (threadIdx.x == 0) atomicMax(maxw + b, __float_as_uint(red[0]));
}

__global__ void k_awd2(const float* __restrict__ awdt, const unsigned int* __restrict__ maxw,
                       float* __restrict__ awd_out) {
    int i = blockIdx.x * 256 + threadIdx.x;  // over BB*NP
    int b = i >> 16;
    awd_out[i] = awdt[i] / __uint_as_float(maxw[b]);
}

// overwrite tok (out_x region) with relu(tokn) in place
__global__ void k_relutok(float* __restrict__ tok, const float* __restrict__ abuf,
                          const float* __restrict__ bbuf) {
    size_t i = (size_t)blockIdx.x * 256 + threadIdx.x;  // float4 index
    int k4 = (int)(i & 63) * 4;
    float4 a = *(const float4*)(abuf + k4);
    float4 bb = *(const float4*)(bbuf + k4);
    float4 v = ((float4*)tok)[i];
    v.x = fmaxf(fmaf(a.x, v.x, bb.x), 0.f);
    v.y = fmaxf(fmaf(a.y, v.y, bb.y), 0.f);
    v.z = fmaxf(fmaf(a.z, v.z, bb.z), 0.f);
    v.w = fmaxf(fmaf(a.w, v.w, bb.w), 0.f);
    ((float4*)tok)[i] = v;
}

extern "C" void kernel_launch(void* const* d_in, const int* in_sizes, int n_in,
                              void* d_out, int out_size, void* d_ws, size_t ws_size,
                              hipStream_t stream) {
    const float* x        = (const float*)d_in[0];
    const float* loc      = (const float*)d_in[1];
    const int*   idx_agg  = (const int*)d_in[2];
    const float* aggw     = (const float*)d_in[3];
    const float* conv_w   = (const float*)d_in[4];
    const float* conv_b   = (const float*)d_in[5];
    const float* skip_w   = (const float*)d_in[6];
    const float* bn_gamma = (const float*)d_in[7];
    const float* bn_beta  = (const float*)d_in[8];
    const float* conf_w   = (const float*)d_in[9];
    const float* conf_b   = (const float*)d_in[10];

    float* ws      = (float*)d_ws;
    float* ssum    = ws + SSUM_OFF;
    float* cnt     = ws + CNT_OFF;
    float* num2    = ws + NUM2_OFF;
    float* den2    = ws + DEN2_OFF;
    float* den1    = ws + DEN1_OFF;
    float* bnsum   = ws + BNSUM_OFF;
    float* bnsq    = ws + BNSQ_OFF;
    unsigned int* maxw = (unsigned int*)(ws + MAXW_OFF);
    float* ybuf    = ws + Y_OFF;
    float* awdt    = ws + AWDT_OFF;
    float* abuf    = ws + ABUF_OFF;
    float* bbuf    = ws + BBUF_OFF;
    float* cwa     = ws + CWA_OFF;
    float* c0      = ws + C0_OFF;
    float* swt     = ws + SWT_OFF;
    int*   cell256 = (int*)(ws + CELL256_OFF);
    int*   cell64  = (int*)(ws + CELL64_OFF);

    float* out       = (float*)d_out;
    float* out_xdown = out;                                    // [4,4096,256]
    float* out_x     = out + (size_t)BB * NS * COUT;           // [4,16384,256] (tok staging -> relu(tokn))
    float* out_conf  = out_x + (size_t)BB * NTOK * COUT;       // [4,16384,1]
    float* out_awd   = out_conf + (size_t)BB * NTOK;           // [4,65536,1]
    float* out_idx   = out_awd + (size_t)BB * NP;              // [4,65536] written as float

    // zero accumulators (ws is poisoned 0xAA every call) + tok accumulator in d_out
    hipMemsetAsync(d_ws, 0, ZERO_FLOATS * sizeof(float), stream);
    hipMemsetAsync(out_x, 0, (size_t)BB * NTOK * COUT * sizeof(float), stream);

    k_cells<<<BB * NP / 256, 256, 0, stream>>>(loc, cell256, cell64);
    k_transpose_skip<<<(COUT * CIN) / 256, 256, 0, stream>>>(skip_w, swt);
    k_scatter_map<<<BB * NP / 8, 256, 0, stream>>>(x, idx_agg, cell256, ssum, cnt);
    k_conv<<<BB * HD * (WD / 32), 256, 0, stream>>>(ssum, cnt, conv_w, conv_b, ybuf);
    k_map2tok<<<BB * NP / 4, 256, 0, stream>>>(ybuf, loc, idx_agg, aggw, out_x, den1);
    k_tok<<<BB * NTOK / 32, 256, 0, stream>>>(x, swt, den1, out_x);
    k_bnstats<<<BB * NTOK / 256, 256, 0, stream>>>(out_x, bnsum, bnsq);
    k_bnparams<<<1, 256, 0, stream>>>(bnsum, bnsq, bn_gamma, bn_beta, conf_w, conf_b,
                                      abuf, bbuf, cwa, c0);
    k_conf<<<BB * NTOK / 16, 256, 0, stream>>>(out_x, cwa, c0, out_conf);
    k_cluster<<<BB * NP / 4, 256, 0, stream>>>(out_x, out_conf, idx_agg, cell64,
                                               abuf, bbuf, num2, den2);
    k_xdown<<<BB * NS * COUT / 4 / 256, 256, 0, stream>>>(num2, den2, out_xdown);
    k_awd1<<<BB * 64, 256, 0, stream>>>(out_conf, den2, idx_agg, cell64, aggw,
                                        awdt, out_idx, maxw);
    k_awd2<<<BB * NP / 256, 256, 0, stream>>>(awdt, maxw, out_awd);
    k_relutok<<<BB * NTOK * COUT / 4 / 256, 256, 0, stream>>>(out_x, abuf, bbuf);
}

// Round 2
// 1312.134 us; speedup vs baseline: 1.2731x; 1.2731x over previous
//
#include <hip/hip_runtime.h>
#include <hip/hip_bf16.h>
#include <math.h>

// Problem constants (fixed by setup_inputs)
#define BB    4
#define NTOK  16384
#define CIN   128
#define COUT  256
#define HM    256
#define WM    256
#define NP    65536      // HM*WM original points per batch
#define HD    128
#define WD    128
#define HC    64
#define WC    64
#define NS    4096       // HC*WC
#define EPS   1e-6f
#define BNEPS 1e-5f

typedef __attribute__((ext_vector_type(8))) short bfrag8;
typedef __attribute__((ext_vector_type(4))) float ffrag4;

// ---------------- workspace layout (floats) ----------------
// zeroed block first (one memset), then non-zeroed scratch
static constexpr size_t SSUM_OFF   = 0;                                   // BB*NP*CIN raw scatter sums; DEAD after k_norm -> ybuf aliases it
static constexpr size_t CNT_OFF    = SSUM_OFF + (size_t)BB * NP * CIN;    // BB*NP
static constexpr size_t NUM2_OFF   = CNT_OFF + (size_t)BB * NP;           // BB*NS*COUT
static constexpr size_t DEN2_OFF   = NUM2_OFF + (size_t)BB * NS * COUT;   // BB*NS
static constexpr size_t DEN1_OFF   = DEN2_OFF + (size_t)BB * NS;          // BB*NTOK
static constexpr size_t BNSUM_OFF  = DEN1_OFF + (size_t)BB * NTOK;        // 256
static constexpr size_t BNSQ_OFF   = BNSUM_OFF + 256;                     // 256
static constexpr size_t MAXW_OFF   = BNSQ_OFF + 256;                      // 4 (uint bits of positive float max)
static constexpr size_t ZERO_FLOATS = MAXW_OFF + 4;
static constexpr size_t Y_OFF      = SSUM_OFF;                            // BB*HD*WD*COUT, aliases dead ssum
static constexpr size_t AWDT_OFF   = (ZERO_FLOATS + 255) & ~(size_t)255;  // BB*NP
static constexpr size_t ABUF_OFF   = AWDT_OFF + (size_t)BB * NP;          // 256
static constexpr size_t BBUF_OFF   = ABUF_OFF + 256;                      // 256
static constexpr size_t CWA_OFF    = BBUF_OFF + 256;                      // 256
static constexpr size_t C0_OFF     = CWA_OFF + 256;                       // 1 (padded to 256)
static constexpr size_t SWT_OFF    = C0_OFF + 256;                        // CIN*COUT  skip_w^T [ci][co]
static constexpr size_t CELL256_OFF = SWT_OFF + (size_t)CIN * COUT;       // BB*NP ints
static constexpr size_t CELL64_OFF  = CELL256_OFF + (size_t)BB * NP;      // BB*NP ints
static constexpr size_t XMAPN_OFF  = CELL64_OFF + (size_t)BB * NP;        // BB*NP*CIN bf16 (counted in floats /2)
static constexpr size_t WFRAG_OFF  = XMAPN_OFF + (size_t)BB * NP * CIN / 2; // 9*4*16*512 bf16 /2 floats

// ---------------- kernels ----------------

__device__ __forceinline__ unsigned short f2bf(float f) {
    unsigned int u = __float_as_uint(f);
    return (unsigned short)((u + 0x7FFFu + ((u >> 16) & 1u)) >> 16);
}

// grid cell indices for both grids (matches jnp.round = RNE via rintf)
__global__ void k_cells(const float* __restrict__ loc, int* __restrict__ cell256,
                        int* __restrict__ cell64) {
    int i = blockIdx.x * 256 + threadIdx.x;   // over BB*NP
    float lx = fminf(fmaxf(loc[2 * (size_t)i], -1.f), 1.f);
    float ly = fminf(fmaxf(loc[2 * (size_t)i + 1], -1.f), 1.f);
    int px = (int)rintf(0.5f * (lx + 1.f) * WM - 0.5f);
    px = min(max(px, 0), WM - 1);
    int py = (int)rintf(0.5f * (ly + 1.f) * HM - 0.5f);
    py = min(max(py, 0), HM - 1);
    cell256[i] = py * WM + px;
    int qx = (int)rintf(0.5f * (lx + 1.f) * WC - 0.5f);
    qx = min(max(qx, 0), WC - 1);
    int qy = (int)rintf(0.5f * (ly + 1.f) * HC - 0.5f);
    qy = min(max(qy, 0), HC - 1);
    cell64[i] = qy * WC + qx;
}

__global__ void k_transpose_skip(const float* __restrict__ sw, float* __restrict__ swt) {
    int i = blockIdx.x * 256 + threadIdx.x;   // over COUT*CIN
    int k = i / CIN, c = i % CIN;
    swt[(size_t)c * COUT + k] = sw[i];
}

// token2map scatter: ssum[b,cell,:] += x[b,idx_agg,:]; cnt[b,cell] += 1
__global__ __launch_bounds__(256) void k_scatter_map(const float* __restrict__ x,
                                                     const int* __restrict__ idx_agg,
                                                     const int* __restrict__ cell256,
                                                     float* __restrict__ ssum,
                                                     float* __restrict__ cnt) {
    int gp = blockIdx.x * 8 + (threadIdx.x >> 5);   // point index over BB*NP
    int lane = threadIdx.x & 31;                    // 32 lanes x float4 = 128 ch
    int b = gp >> 16;
    int cell = cell256[gp];
    int ia = idx_agg[gp];
    float4 v = *(const float4*)(x + ((size_t)b * NTOK + ia) * CIN + lane * 4);
    float* dst = ssum + ((size_t)b * NP + cell) * CIN + lane * 4;
    atomicAdd(dst + 0, v.x);
    atomicAdd(dst + 1, v.y);
    atomicAdd(dst + 2, v.z);
    atomicAdd(dst + 3, v.w);
    if (lane == 0) atomicAdd(cnt + (size_t)b * NP + cell, 1.0f);
}

// normalize scatter sums by count and cast to bf16 map
__global__ void k_norm(const float* __restrict__ ssum, const float* __restrict__ cnt,
                       unsigned short* __restrict__ xmapn) {
    size_t i = (size_t)blockIdx.x * 256 + threadIdx.x;  // float4 index over BB*NP*CIN/4
    float4 v = ((const float4*)ssum)[i];
    float inv = 1.0f / (cnt[i >> 5] + EPS);
    ushort4 o;
    o.x = f2bf(v.x * inv);
    o.y = f2bf(v.y * inv);
    o.z = f2bf(v.z * inv);
    o.w = f2bf(v.w * inv);
    ((ushort4*)xmapn)[i] = o;
}

// pre-swizzle conv weights into MFMA 16x16x32 B-fragment lane layout:
// wfrag[((khw*4+kc)*16+nt)*512 + lane*8 + j] = bf16(conv_w[khw][kc*32+(lane>>4)*8+j][nt*16+(lane&15)])
__global__ void k_wfrag(const float* __restrict__ cw, unsigned short* __restrict__ wfrag) {
    int i = blockIdx.x * 256 + threadIdx.x;  // over 9*4*16*512
    int j = i & 7;
    int lane = (i >> 3) & 63;
    int nt = (i >> 9) & 15;
    int kc = (i >> 13) & 3;
    int khw = i >> 15;
    int c = kc * 32 + ((lane >> 4) << 3) + j;
    int n = nt * 16 + (lane & 15);
    wfrag[i] = f2bf(cw[((size_t)khw * CIN + c) * COUT + n]);
}

// 3x3 stride-2 pad-1 conv as implicit GEMM on bf16 MFMA 16x16x32.
// Block: 64 output pixels (fixed oh, half a row) x 256 cout; 4 waves, wave w
// owns cout strip [w*64, w*64+64). Per-wave 4x4 fragments of 16x16, fp32 acc.
// Input row window staged per-kh in LDS, split by pixel parity (kw parity),
// row stride 136 bf16 -> 2-way bank aliasing only (free).
__global__ __launch_bounds__(256) void k_convmf(const unsigned short* __restrict__ xmapn,
                                                const unsigned short* __restrict__ wfrag,
                                                const float* __restrict__ cb,
                                                float* __restrict__ y) {
    int bz = blockIdx.x;
    int ow0 = (bz & 1) * 64;
    int oh = (bz >> 1) & (HD - 1);
    int b = bz >> 8;
    int tid = threadIdx.x;
    int w = tid >> 6, lane = tid & 63;
    int n0 = w * 64;

    __shared__ unsigned short s_even[65 * 136];
    __shared__ unsigned short s_odd[64 * 136];

    ffrag4 acc[4][4];
#pragma unroll
    for (int mt = 0; mt < 4; ++mt)
#pragma unroll
        for (int nt = 0; nt < 4; ++nt) {
            ffrag4 z = {0.f, 0.f, 0.f, 0.f};
            acc[mt][nt] = z;
        }

    int iw0 = 2 * ow0 - 1;
    int lm = lane & 15;           // m within 16 (A rows) / n within 16 (B cols)
    int lq = lane >> 4;           // quad
    int cbase = lq << 3;          // k offset within 32-chunk

    for (int kh = 0; kh < 3; ++kh) {
        int ih = 2 * oh - 1 + kh;
        __syncthreads();
        {
            const unsigned short* rowb =
                xmapn + ((size_t)b * NP + (size_t)ih * WM) * CIN;
            bool ihok = (ih >= 0 && ih < HM);
            for (int idx = tid; idx < 129 * 16; idx += 256) {
                int pix = idx >> 4;
                int c8 = (idx & 15) * 8;
                int iw = iw0 + pix;
                uint4 v = make_uint4(0u, 0u, 0u, 0u);
                if (ihok && iw >= 0 && iw < WM)
                    v = *(const uint4*)(rowb + (size_t)iw * CIN + c8);
                unsigned short* dst = (pix & 1)
                    ? &s_odd[(size_t)((pix - 1) >> 1) * 136 + c8]
                    : &s_even[(size_t)(pix >> 1) * 136 + c8];
                *(uint4*)dst = v;
            }
        }
        __syncthreads();
#pragma unroll
        for (int kw = 0; kw < 3; ++kw) {
            int khw = kh * 3 + kw;
#pragma unroll
            for (int kc = 0; kc < 4; ++kc) {
                int c = kc * 32 + cbase;
                bfrag8 af[4];
#pragma unroll
                for (int mt = 0; mt < 4; ++mt) {
                    int m = mt * 16 + lm;
                    const unsigned short* src;
                    if (kw == 1)      src = &s_odd[(size_t)m * 136 + c];
                    else if (kw == 0) src = &s_even[(size_t)m * 136 + c];
                    else              src = &s_even[(size_t)(m + 1) * 136 + c];
                    af[mt] = *(const bfrag8*)(const void*)src;
                }
                const unsigned short* wb =
                    wfrag + ((size_t)((khw * 4 + kc) * 16) + w * 4) * 512 + lane * 8;
#pragma unroll
                for (int nt = 0; nt < 4; ++nt) {
                    bfrag8 bf = *(const bfrag8*)(const void*)(wb + (size_t)nt * 512);
#pragma unroll
                    for (int mt = 0; mt < 4; ++mt)
                        acc[mt][nt] = __builtin_amdgcn_mfma_f32_16x16x32_bf16(
                            af[mt], bf, acc[mt][nt], 0, 0, 0);
                }
            }
        }
    }

    // epilogue: D row = (lane>>4)*4 + r (pixel), col = lane&15 (cout)
    float* yb = y + (((size_t)b * HD + oh) * WD + ow0) * COUT;
#pragma unroll
    for (int nt = 0; nt < 4; ++nt) {
        int n = n0 + nt * 16 + lm;
        float bias = cb[n];
#pragma unroll
        for (int mt = 0; mt < 4; ++mt) {
#pragma unroll
            for (int r = 0; r < 4; ++r) {
                int m = mt * 16 + lq * 4 + r;
                yb[(size_t)m * COUT + n] = acc[mt][nt][r] + bias;
            }
        }
    }
}

// map2token: bilinear sample y at each point, atomic scatter to token nums
__global__ __launch_bounds__(256) void k_map2tok(const float* __restrict__ y,
                                                 const float* __restrict__ loc,
                                                 const int* __restrict__ idx_agg,
                                                 const float* __restrict__ aggw,
                                                 float* __restrict__ num,
                                                 float* __restrict__ den1) {
    int k = threadIdx.x;
    int gp0 = blockIdx.x * 4;
    for (int g = 0; g < 4; ++g) {
        int gp = gp0 + g;
        int b = gp >> 16;
        float lx = fminf(fmaxf(loc[2 * (size_t)gp], -1.f), 1.f);
        float ly = fminf(fmaxf(loc[2 * (size_t)gp + 1], -1.f), 1.f);
        float fx = fminf(fmaxf(0.5f * (lx + 1.f) * WD - 0.5f, 0.f), (float)(WD - 1));
        float fy = fminf(fmaxf(0.5f * (ly + 1.f) * HD - 0.5f, 0.f), (float)(HD - 1));
        float x0f = floorf(fx), y0f = floorf(fy);
        float wx = fx - x0f, wy = fy - y0f;
        int x0 = (int)x0f, y0 = (int)y0f;
        int x1 = min(x0 + 1, WD - 1), y1 = min(y0 + 1, HD - 1);
        const float* ybase = y + (size_t)b * (HD * WD * COUT);
        float v00 = ybase[((size_t)y0 * WD + x0) * COUT + k];
        float v01 = ybase[((size_t)y0 * WD + x1) * COUT + k];
        float v10 = ybase[((size_t)y1 * WD + x0) * COUT + k];
        float v11 = ybase[((size_t)y1 * WD + x1) * COUT + k];
        float f = (1.f - wx) * (1.f - wy) * v00 + wx * (1.f - wy) * v01 +
                  (1.f - wx) * wy * v10 + wx * wy * v11;
        float w = aggw[gp];
        int ia = idx_agg[gp];
        atomicAdd(num + ((size_t)b * NTOK + ia) * COUT + k, f * w);
        if (k == 0) atomicAdd(den1 + (size_t)b * NTOK + ia, w);
    }
}

// tok = num/(den1+eps) + x @ skip_w^T   (in place over the num buffer = out_x region)
__global__ __launch_bounds__(256) void k_tok(const float* __restrict__ x,
                                             const float* __restrict__ swt,
                                             const float* __restrict__ den1,
                                             float* __restrict__ tok) {
    int t0 = blockIdx.x * 32;
    int tid = threadIdx.x;
    int nt = tid & 63, pt = tid >> 6;
    int n = nt * 4;
    __shared__ float xs[32 * CIN];
    for (int idx = tid; idx < 32 * 32; idx += 256) {
        int p = idx >> 5, c4 = idx & 31;
        *(float4*)(xs + p * CIN + c4 * 4) =
            *(const float4*)(x + ((size_t)(t0 + p)) * CIN + c4 * 4);
    }
    __syncthreads();
    float acc[4][8];
#pragma unroll
    for (int i = 0; i < 4; ++i)
#pragma unroll
        for (int j = 0; j < 8; ++j) acc[i][j] = 0.f;
#pragma unroll 4
    for (int c = 0; c < CIN; ++c) {
        float4 w4 = *(const float4*)(swt + (size_t)c * COUT + n);
#pragma unroll
        for (int j = 0; j < 8; ++j) {
            float a = xs[(pt * 8 + j) * CIN + c];
            acc[0][j] = fmaf(a, w4.x, acc[0][j]);
            acc[1][j] = fmaf(a, w4.y, acc[1][j]);
            acc[2][j] = fmaf(a, w4.z, acc[2][j]);
            acc[3][j] = fmaf(a, w4.w, acc[3][j]);
        }
    }
#pragma unroll
    for (int j = 0; j < 8; ++j) {
        int tkn = t0 + pt * 8 + j;
        float inv = 1.f / (den1[tkn] + EPS);
        float* pp = tok + (size_t)tkn * COUT + n;
        float4 v = *(float4*)pp;
        v.x = v.x * inv + acc[0][j];
        v.y = v.y * inv + acc[1][j];
        v.z = v.z * inv + acc[2][j];
        v.w = v.w * inv + acc[3][j];
        *(float4*)pp = v;
    }
}

__global__ void k_bnstats(const float* __restrict__ tok, float* __restrict__ bnsum,
                          float* __restrict__ bnsq) {
    int k = threadIdx.x;
    size_t t0 = (size_t)blockIdx.x * 256;
    float s = 0.f, sq = 0.f;
    for (int t = 0; t < 256; ++t) {
        float v = tok[(t0 + t) * COUT + k];
        s += v;
        sq = fmaf(v, v, sq);
    }
    atomicAdd(bnsum + k, s);
    atomicAdd(bnsq + k, sq);
}

// per-channel BN affine: a=gamma/sqrt(var+eps), bb=beta-mu*a; fold conf head
__global__ void k_bnparams(const float* __restrict__ bnsum, const float* __restrict__ bnsq,
                           const float* __restrict__ gamma, const float* __restrict__ beta,
                           const float* __restrict__ confw, const float* __restrict__ confb,
                           float* __restrict__ abuf, float* __restrict__ bbuf,
                           float* __restrict__ cwa, float* __restrict__ c0) {
    int k = threadIdx.x;
    const float cntv = (float)(BB * NTOK);
    float mu = bnsum[k] / cntv;
    float var = bnsq[k] / cntv - mu * mu;
    float a = gamma[k] * rsqrtf(var + BNEPS);
    float bbv = beta[k] - mu * a;
    abuf[k] = a;
    bbuf[k] = bbv;
    float cw = confw[k];
    cwa[k] = a * cw;
    __shared__ float red[256];
    red[k] = bbv * cw;
    __syncthreads();
    for (int s = 128; s > 0; s >>= 1) {
        if (k < s) red[k] += red[k + s];
        __syncthreads();
    }
    if (k == 0) c0[0] = red[0] + confb[0];
}

// conf = tokn @ conf_w^T + conf_b, folded:  dot(tok, cwa) + c0
__global__ void k_conf(const float* __restrict__ tok, const float* __restrict__ cwa,
                       const float* __restrict__ c0v, float* __restrict__ conf_out) {
    int tid = threadIdx.x;
    int tkn = blockIdx.x * 16 + (tid >> 4);
    int kc = (tid & 15) * 16;
    const float* row = tok + (size_t)tkn * COUT + kc;
    float s = 0.f;
#pragma unroll
    for (int i = 0; i < 16; i += 4) {
        float4 v = *(const float4*)(row + i);
        float4 w = *(const float4*)(cwa + kc + i);
        s += v.x * w.x + v.y * w.y + v.z * w.z + v.w * w.w;
    }
    for (int off = 8; off > 0; off >>= 1) s += __shfl_down(s, off, 16);
    if ((tid & 15) == 0) conf_out[tkn] = s + c0v[0];
}

// token_cluster_grid scatter: num2[b,cell,:] += tokn[b,ia,:]*w ; den2 += w
__global__ __launch_bounds__(256) void k_cluster(const float* __restrict__ tok,
                                                 const float* __restrict__ conf,
                                                 const int* __restrict__ idx_agg,
                                                 const int* __restrict__ cell64,
                                                 const float* __restrict__ abuf,
                                                 const float* __restrict__ bbuf,
                                                 float* __restrict__ num2,
                                                 float* __restrict__ den2) {
    int k = threadIdx.x;
    float a = abuf[k], bbv = bbuf[k];
    int gp0 = blockIdx.x * 4;
    for (int g = 0; g < 4; ++g) {
        int gp = gp0 + g;
        int b = gp >> 16;
        int ia = idx_agg[gp];
        int cell = cell64[gp];
        float w = expf(conf[(size_t)b * NTOK + ia]);
        float tv = tok[((size_t)b * NTOK + ia) * COUT + k];
        float f = fmaf(a, tv, bbv);
        atomicAdd(num2 + ((size_t)b * NS + cell) * COUT + k, f * w);
        if (k == 0) atomicAdd(den2 + (size_t)b * NS + cell, w);
    }
}

__global__ void k_xdown(const float* __restrict__ num2, const float* __restrict__ den2,
                        float* __restrict__ xdown) {
    size_t i = (size_t)blockIdx.x * 256 + threadIdx.x;  // float4 index over BB*NS*COUT/4
    float4 v = ((const float4*)num2)[i];
    float inv = 1.f / (den2[i >> 6] + EPS);
    v.x = fmaxf(v.x * inv, 0.f);
    v.y = fmaxf(v.y * inv, 0.f);
    v.z = fmaxf(v.z * inv, 0.f);
    v.w = fmaxf(v.w * inv, 0.f);
    ((float4*)xdown)[i] = v;
}

// agg_weight_down numerator + per-batch max (positive floats -> uint atomicMax)
__global__ void k_awd1(const float* __restrict__ conf, const float* __restrict__ den2,
                       const int* __restrict__ idx_agg, const int* __restrict__ cell64,
                       const float* __restrict__ aggw, float* __restrict__ awdt,
                       float* __restrict__ idx_out_f, unsigned int* __restrict__ maxw) {
    int b = blockIdx.x >> 6;
    int chunk = blockIdx.x & 63;
    int base = b * NP + chunk * 1024;
    float lmax = 0.f;
    for (int t = threadIdx.x; t < 1024; t += 256) {
        int gp = base + t;
        int ia = idx_agg[gp];
        int cell = cell64[gp];
        float w = expf(conf[(size_t)b * NTOK + ia]);
        float wt = w / (den2[(size_t)b * NS + cell] + EPS);
        float tv = aggw[gp] * wt;
        awdt[gp] = tv;
        idx_out_f[gp] = (float)cell;
        lmax = fmaxf(lmax, tv);
    }
    __shared__ float red[256];
    red[threadIdx.x] = lmax;
    __syncthreads();
    for (int s = 128; s > 0; s >>= 1) {
        if (threadIdx.x < s) red[threadIdx.x] = fmaxf(red[threadIdx.x], red[threadIdx.x + s]);
        __syncthreads();
    }
    if (threadIdx.x == 0) atomicMax(maxw + b, __float_as_uint(red[0]));
}

__global__ void k_awd2(const float* __restrict__ awdt, const unsigned int* __restrict__ maxw,
                       float* __restrict__ awd_out) {
    int i = blockIdx.x * 256 + threadIdx.x;  // over BB*NP
    int b = i >> 16;
    awd_out[i] = awdt[i] / __uint_as_float(maxw[b]);
}

// overwrite tok (out_x region) with relu(tokn) in place
__global__ void k_relutok(float* __restrict__ tok, const float* __restrict__ abuf,
                          const float* __restrict__ bbuf) {
    size_t i = (size_t)blockIdx.x * 256 + threadIdx.x;  // float4 index
    int k4 = (int)(i & 63) * 4;
    float4 a = *(const float4*)(abuf + k4);
    float4 bb = *(const float4*)(bbuf + k4);
    float4 v = ((float4*)tok)[i];
    v.x = fmaxf(fmaf(a.x, v.x, bb.x), 0.f);
    v.y = fmaxf(fmaf(a.y, v.y, bb.y), 0.f);
    v.z = fmaxf(fmaf(a.z, v.z, bb.z), 0.f);
    v.w = fmaxf(fmaf(a.w, v.w, bb.w), 0.f);
    ((float4*)tok)[i] = v;
}

extern "C" void kernel_launch(void* const* d_in, const int* in_sizes, int n_in,
                              void* d_out, int out_size, void* d_ws, size_t ws_size,
                              hipStream_t stream) {
    const float* x        = (const float*)d_in[0];
    const float* loc      = (const float*)d_in[1];
    const int*   idx_agg  = (const int*)d_in[2];
    const float* aggw     = (const float*)d_in[3];
    const float* conv_w   = (const float*)d_in[4];
    const float* conv_b   = (const float*)d_in[5];
    const float* skip_w   = (const float*)d_in[6];
    const float* bn_gamma = (const float*)d_in[7];
    const float* bn_beta  = (const float*)d_in[8];
    const float* conf_w   = (const float*)d_in[9];
    const float* conf_b   = (const float*)d_in[10];

    float* ws      = (float*)d_ws;
    float* ssum    = ws + SSUM_OFF;
    float* cnt     = ws + CNT_OFF;
    float* num2    = ws + NUM2_OFF;
    float* den2    = ws + DEN2_OFF;
    float* den1    = ws + DEN1_OFF;
    float* bnsum   = ws + BNSUM_OFF;
    float* bnsq    = ws + BNSQ_OFF;
    unsigned int* maxw = (unsigned int*)(ws + MAXW_OFF);
    float* ybuf    = ws + Y_OFF;          // aliases ssum (dead after k_norm)
    float* awdt    = ws + AWDT_OFF;
    float* abuf    = ws + ABUF_OFF;
    float* bbuf    = ws + BBUF_OFF;
    float* cwa     = ws + CWA_OFF;
    float* c0      = ws + C0_OFF;
    float* swt     = ws + SWT_OFF;
    int*   cell256 = (int*)(ws + CELL256_OFF);
    int*   cell64  = (int*)(ws + CELL64_OFF);
    unsigned short* xmapn = (unsigned short*)(ws + XMAPN_OFF);
    unsigned short* wfrag = (unsigned short*)(ws + WFRAG_OFF);

    float* out       = (float*)d_out;
    float* out_xdown = out;                                    // [4,4096,256]
    float* out_x     = out + (size_t)BB * NS * COUT;           // [4,16384,256] (tok staging -> relu(tokn))
    float* out_conf  = out_x + (size_t)BB * NTOK * COUT;       // [4,16384,1]
    float* out_awd   = out_conf + (size_t)BB * NTOK;           // [4,65536,1]
    float* out_idx   = out_awd + (size_t)BB * NP;              // [4,65536] written as float

    // zero accumulators (ws is poisoned 0xAA every call) + tok accumulator in d_out
    hipMemsetAsync(d_ws, 0, ZERO_FLOATS * sizeof(float), stream);
    hipMemsetAsync(out_x, 0, (size_t)BB * NTOK * COUT * sizeof(float), stream);

    k_cells<<<BB * NP / 256, 256, 0, stream>>>(loc, cell256, cell64);
    k_transpose_skip<<<(COUT * CIN) / 256, 256, 0, stream>>>(skip_w, swt);
    k_wfrag<<<9 * 4 * 16 * 512 / 256, 256, 0, stream>>>(conv_w, wfrag);
    k_scatter_map<<<BB * NP / 8, 256, 0, stream>>>(x, idx_agg, cell256, ssum, cnt);
    k_norm<<<BB * NP * CIN / 4 / 256, 256, 0, stream>>>(ssum, cnt, xmapn);
    k_convmf<<<BB * HD * 2, 256, 0, stream>>>(xmapn, wfrag, conv_b, ybuf);
    k_map2tok<<<BB * NP / 4, 256, 0, stream>>>(ybuf, loc, idx_agg, aggw, out_x, den1);
    k_tok<<<BB * NTOK / 32, 256, 0, stream>>>(x, swt, den1, out_x);
    k_bnstats<<<BB * NTOK / 256, 256, 0, stream>>>(out_x, bnsum, bnsq);
    k_bnparams<<<1, 256, 0, stream>>>(bnsum, bnsq, bn_gamma, bn_beta, conf_w, conf_b,
                                      abuf, bbuf, cwa, c0);
    k_conf<<<BB * NTOK / 16, 256, 0, stream>>>(out_x, cwa, c0, out_conf);
    k_cluster<<<BB * NP / 4, 256, 0, stream>>>(out_x, out_conf, idx_agg, cell64,
                                               abuf, bbuf, num2, den2);
    k_xdown<<<BB * NS * COUT / 4 / 256, 256, 0, stream>>>(num2, den2, out_xdown);
    k_awd1<<<BB * 64, 256, 0, stream>>>(out_conf, den2, idx_agg, cell64, aggw,
                                        awdt, out_idx, maxw);
    k_awd2<<<BB * NP / 256, 256, 0, stream>>>(awdt, maxw, out_awd);
    k_relutok<<<BB * NTOK * COUT / 4 / 256, 256, 0, stream>>>(out_x, abuf, bbuf);
}

// Round 3
// 624.619 us; speedup vs baseline: 2.6744x; 2.1007x over previous
//
#include <hip/hip_runtime.h>
#include <hip/hip_bf16.h>
#include <math.h>

// Problem constants (fixed by setup_inputs)
#define BB    4
#define NTOK  16384
#define CIN   128
#define COUT  256
#define HM    256
#define WM    256
#define NP    65536      // HM*WM original points per batch
#define HD    128
#define WD    128
#define HC    64
#define WC    64
#define NS    4096       // HC*WC
#define EPS   1e-6f
#define BNEPS 1e-5f

// CSR segment bases (concatenated target domains)
#define SEG_TOK  (BB * NP)                  // 262144
#define SEG_64   (SEG_TOK + BB * NTOK)      // 327680
#define NSEG     (SEG_64 + BB * NS)         // 344064 = 336 * 1024

typedef __attribute__((ext_vector_type(8))) short bfrag8;
typedef __attribute__((ext_vector_type(4))) float ffrag4;

// ---------------- workspace layout (floats) ----------------
// zeroed block first (one small memset), then non-zeroed scratch
static constexpr size_t BNSUM_OFF  = 0;                                   // 256
static constexpr size_t BNSQ_OFF   = BNSUM_OFF + 256;                     // 256
static constexpr size_t MAXW_OFF   = BNSQ_OFF + 256;                      // 4 (pad 256)
static constexpr size_t CNTS_OFF   = MAXW_OFF + 256;                      // NSEG ints
static constexpr size_t CURS_OFF   = CNTS_OFF + NSEG;                     // NSEG ints
static constexpr size_t ZERO_FLOATS = CURS_OFF + NSEG;
// non-zeroed:
static constexpr size_t YBUF_OFF   = (ZERO_FLOATS + 255) & ~(size_t)255;  // BB*HD*WD*COUT
static constexpr size_t XMAPN_OFF  = YBUF_OFF + (size_t)BB * HD * WD * COUT; // BB*NP*CIN bf16 -> /2 floats
static constexpr size_t WFRAG_OFF  = XMAPN_OFF + (size_t)BB * NP * CIN / 2;  // 9*4*16*512 bf16 -> /2 floats
static constexpr size_t AWDT_OFF   = WFRAG_OFF + (size_t)9 * 4 * 16 * 512 / 2; // BB*NP
static constexpr size_t ABUF_OFF   = AWDT_OFF + (size_t)BB * NP;          // 256
static constexpr size_t BBUF_OFF   = ABUF_OFF + 256;                      // 256
static constexpr size_t CWA_OFF    = BBUF_OFF + 256;                      // 256
static constexpr size_t C0_OFF     = CWA_OFF + 256;                       // 256
static constexpr size_t SWT_OFF    = C0_OFF + 256;                        // CIN*COUT
static constexpr size_t CELL256_OFF = SWT_OFF + (size_t)CIN * COUT;       // BB*NP ints
static constexpr size_t CELL64_OFF  = CELL256_OFF + (size_t)BB * NP;      // BB*NP ints
static constexpr size_t DEN1_OFF   = CELL64_OFF + (size_t)BB * NP;        // BB*NTOK
static constexpr size_t DEN2_OFF   = DEN1_OFF + (size_t)BB * NTOK;        // BB*NS
static constexpr size_t STARTS_OFF = DEN2_OFF + (size_t)BB * NS;          // NSEG ints
static constexpr size_t BLKSUM_OFF = STARTS_OFF + NSEG;                   // 512 ints
static constexpr size_t BLKEXCL_OFF = BLKSUM_OFF + 512;                   // 512 ints
static constexpr size_t PIDX_OFF   = BLKEXCL_OFF + 512;                   // 3*BB*NP ints

// ---------------- kernels ----------------

__device__ __forceinline__ unsigned short f2bf(float f) {
    unsigned int u = __float_as_uint(f);
    return (unsigned short)((u + 0x7FFFu + ((u >> 16) & 1u)) >> 16);
}

// grid cell indices for both grids (matches jnp.round = RNE via rintf)
__global__ void k_cells(const float* __restrict__ loc, int* __restrict__ cell256,
                        int* __restrict__ cell64) {
    int i = blockIdx.x * 256 + threadIdx.x;   // over BB*NP
    float lx = fminf(fmaxf(loc[2 * (size_t)i], -1.f), 1.f);
    float ly = fminf(fmaxf(loc[2 * (size_t)i + 1], -1.f), 1.f);
    int px = (int)rintf(0.5f * (lx + 1.f) * WM - 0.5f);
    px = min(max(px, 0), WM - 1);
    int py = (int)rintf(0.5f * (ly + 1.f) * HM - 0.5f);
    py = min(max(py, 0), HM - 1);
    cell256[i] = py * WM + px;
    int qx = (int)rintf(0.5f * (lx + 1.f) * WC - 0.5f);
    qx = min(max(qx, 0), WC - 1);
    int qy = (int)rintf(0.5f * (ly + 1.f) * HC - 0.5f);
    qy = min(max(qy, 0), HC - 1);
    cell64[i] = qy * WC + qx;
}

__global__ void k_transpose_skip(const float* __restrict__ sw, float* __restrict__ swt) {
    int i = blockIdx.x * 256 + threadIdx.x;   // over COUT*CIN
    int k = i / CIN, c = i % CIN;
    swt[(size_t)c * COUT + k] = sw[i];
}

// histogram of all three target domains (concatenated)
__global__ void k_hist(const int* __restrict__ cell256, const int* __restrict__ idx_agg,
                       const int* __restrict__ cell64, int* __restrict__ cnts) {
    int gp = blockIdx.x * 256 + threadIdx.x;  // over BB*NP
    int b = gp >> 16;
    atomicAdd(&cnts[b * NP + cell256[gp]], 1);
    atomicAdd(&cnts[SEG_TOK + b * NTOK + idx_agg[gp]], 1);
    atomicAdd(&cnts[SEG_64 + b * NS + cell64[gp]], 1);
}

// 2-level exclusive scan over NSEG = 336*1024 counters
__global__ __launch_bounds__(256) void k_scan1(const int* __restrict__ cnts,
                                               int* __restrict__ starts,
                                               int* __restrict__ blksum) {
    int t = threadIdx.x;
    int base = blockIdx.x * 1024 + t * 4;
    int4 v = *(const int4*)(cnts + base);
    int tsum = v.x + v.y + v.z + v.w;
    __shared__ int s[256];
    s[t] = tsum;
    __syncthreads();
    for (int off = 1; off < 256; off <<= 1) {
        int add = (t >= off) ? s[t - off] : 0;
        __syncthreads();
        s[t] += add;
        __syncthreads();
    }
    int excl = s[t] - tsum;
    int4 o;
    o.x = excl; o.y = excl + v.x; o.z = o.y + v.y; o.w = o.z + v.z;
    *(int4*)(starts + base) = o;
    if (t == 255) blksum[blockIdx.x] = s[255];
}

__global__ __launch_bounds__(512) void k_scan2(const int* __restrict__ blksum,
                                               int* __restrict__ blkexcl) {
    int t = threadIdx.x;
    __shared__ int s[512];
    int v = (t < 336) ? blksum[t] : 0;
    s[t] = v;
    __syncthreads();
    for (int off = 1; off < 512; off <<= 1) {
        int add = (t >= off) ? s[t - off] : 0;
        __syncthreads();
        s[t] += add;
        __syncthreads();
    }
    if (t < 336) blkexcl[t] = s[t] - v;
}

// fill CSR pools: map stores resolved token id, tok stores point id, cell64 stores token id
__global__ void k_fill(const int* __restrict__ cell256, const int* __restrict__ idx_agg,
                       const int* __restrict__ cell64, const int* __restrict__ starts,
                       const int* __restrict__ blkexcl, int* __restrict__ curs,
                       int* __restrict__ pidx) {
    int gp = blockIdx.x * 256 + threadIdx.x;  // over BB*NP
    int b = gp >> 16;
    int ia = idx_agg[gp];
    int t1 = b * NP + cell256[gp];
    int p1 = starts[t1] + blkexcl[t1 >> 10] + atomicAdd(&curs[t1], 1);
    pidx[p1] = ia;
    int t2 = SEG_TOK + b * NTOK + ia;
    int p2 = starts[t2] + blkexcl[t2 >> 10] + atomicAdd(&curs[t2], 1);
    pidx[p2] = gp;
    int t3 = SEG_64 + b * NS + cell64[gp];
    int p3 = starts[t3] + blkexcl[t3 >> 10] + atomicAdd(&curs[t3], 1);
    pidx[p3] = ia;
}

// token2map as gather: per map cell, sum token rows, normalize, cast bf16 (fuses k_norm)
__global__ __launch_bounds__(256) void k_gather_map(const float* __restrict__ x,
                                                    const int* __restrict__ starts,
                                                    const int* __restrict__ blkexcl,
                                                    const int* __restrict__ cnts,
                                                    const int* __restrict__ pidx,
                                                    unsigned short* __restrict__ xmapn) {
    int tgt = blockIdx.x * 8 + (threadIdx.x >> 5);  // over BB*NP
    int lane = threadIdx.x & 31;                    // 32 lanes x float4 = 128 ch
    int b = tgt >> 16;
    int start = starts[tgt] + blkexcl[tgt >> 10];
    int cnt = cnts[tgt];
    float4 acc = make_float4(0.f, 0.f, 0.f, 0.f);
    for (int j = 0; j < cnt; ++j) {
        int tk = pidx[start + j];
        float4 v = *(const float4*)(x + ((size_t)b * NTOK + tk) * CIN + lane * 4);
        acc.x += v.x; acc.y += v.y; acc.z += v.z; acc.w += v.w;
    }
    float inv = 1.0f / ((float)cnt + EPS);
    ushort4 o;
    o.x = f2bf(acc.x * inv);
    o.y = f2bf(acc.y * inv);
    o.z = f2bf(acc.z * inv);
    o.w = f2bf(acc.w * inv);
    *(ushort4*)(xmapn + (size_t)tgt * CIN + lane * 4) = o;
}

// pre-swizzle conv weights into MFMA 16x16x32 B-fragment lane layout
__global__ void k_wfrag(const float* __restrict__ cw, unsigned short* __restrict__ wfrag) {
    int i = blockIdx.x * 256 + threadIdx.x;  // over 9*4*16*512
    int j = i & 7;
    int lane = (i >> 3) & 63;
    int nt = (i >> 9) & 15;
    int kc = (i >> 13) & 3;
    int khw = i >> 15;
    int c = kc * 32 + ((lane >> 4) << 3) + j;
    int n = nt * 16 + (lane & 15);
    wfrag[i] = f2bf(cw[((size_t)khw * CIN + c) * COUT + n]);
}

// 3x3 stride-2 pad-1 conv as implicit GEMM on bf16 MFMA 16x16x32.
__global__ __launch_bounds__(256) void k_convmf(const unsigned short* __restrict__ xmapn,
                                                const unsigned short* __restrict__ wfrag,
                                                const float* __restrict__ cb,
                                                float* __restrict__ y) {
    int bz = blockIdx.x;
    int ow0 = (bz & 1) * 64;
    int oh = (bz >> 1) & (HD - 1);
    int b = bz >> 8;
    int tid = threadIdx.x;
    int w = tid >> 6, lane = tid & 63;
    int n0 = w * 64;

    __shared__ unsigned short s_even[65 * 136];
    __shared__ unsigned short s_odd[64 * 136];

    ffrag4 acc[4][4];
#pragma unroll
    for (int mt = 0; mt < 4; ++mt)
#pragma unroll
        for (int nt = 0; nt < 4; ++nt) {
            ffrag4 z = {0.f, 0.f, 0.f, 0.f};
            acc[mt][nt] = z;
        }

    int iw0 = 2 * ow0 - 1;
    int lm = lane & 15;
    int lq = lane >> 4;
    int cbase = lq << 3;

    for (int kh = 0; kh < 3; ++kh) {
        int ih = 2 * oh - 1 + kh;
        __syncthreads();
        {
            const unsigned short* rowb =
                xmapn + ((size_t)b * NP + (size_t)ih * WM) * CIN;
            bool ihok = (ih >= 0 && ih < HM);
            for (int idx = tid; idx < 129 * 16; idx += 256) {
                int pix = idx >> 4;
                int c8 = (idx & 15) * 8;
                int iw = iw0 + pix;
                uint4 v = make_uint4(0u, 0u, 0u, 0u);
                if (ihok && iw >= 0 && iw < WM)
                    v = *(const uint4*)(rowb + (size_t)iw * CIN + c8);
                unsigned short* dst = (pix & 1)
                    ? &s_odd[(size_t)((pix - 1) >> 1) * 136 + c8]
                    : &s_even[(size_t)(pix >> 1) * 136 + c8];
                *(uint4*)dst = v;
            }
        }
        __syncthreads();
#pragma unroll
        for (int kw = 0; kw < 3; ++kw) {
            int khw = kh * 3 + kw;
#pragma unroll
            for (int kc = 0; kc < 4; ++kc) {
                int c = kc * 32 + cbase;
                bfrag8 af[4];
#pragma unroll
                for (int mt = 0; mt < 4; ++mt) {
                    int m = mt * 16 + lm;
                    const unsigned short* src;
                    if (kw == 1)      src = &s_odd[(size_t)m * 136 + c];
                    else if (kw == 0) src = &s_even[(size_t)m * 136 + c];
                    else              src = &s_even[(size_t)(m + 1) * 136 + c];
                    af[mt] = *(const bfrag8*)(const void*)src;
                }
                const unsigned short* wb =
                    wfrag + ((size_t)((khw * 4 + kc) * 16) + w * 4) * 512 + lane * 8;
#pragma unroll
                for (int nt = 0; nt < 4; ++nt) {
                    bfrag8 bf = *(const bfrag8*)(const void*)(wb + (size_t)nt * 512);
#pragma unroll
                    for (int mt = 0; mt < 4; ++mt)
                        acc[mt][nt] = __builtin_amdgcn_mfma_f32_16x16x32_bf16(
                            af[mt], bf, acc[mt][nt], 0, 0, 0);
                }
            }
        }
    }

    float* yb = y + (((size_t)b * HD + oh) * WD + ow0) * COUT;
#pragma unroll
    for (int nt = 0; nt < 4; ++nt) {
        int n = n0 + nt * 16 + lm;
        float bias = cb[n];
#pragma unroll
        for (int mt = 0; mt < 4; ++mt) {
#pragma unroll
            for (int r = 0; r < 4; ++r) {
                int m = mt * 16 + lq * 4 + r;
                yb[(size_t)m * COUT + n] = acc[mt][nt][r] + bias;
            }
        }
    }
}

// map2token as gather: per token, bilinear-sample its points, direct write num/den
__global__ __launch_bounds__(256) void k_gather_tok(const float* __restrict__ y,
                                                    const float* __restrict__ loc,
                                                    const float* __restrict__ aggw,
                                                    const int* __restrict__ starts,
                                                    const int* __restrict__ blkexcl,
                                                    const int* __restrict__ cnts,
                                                    const int* __restrict__ pidx,
                                                    float* __restrict__ num_out,
                                                    float* __restrict__ den1) {
    int wv = threadIdx.x >> 6, lane = threadIdx.x & 63;  // 64 lanes x float4 = 256 ch
    int tl = blockIdx.x * 4 + wv;                        // over BB*NTOK
    int b = tl >> 14;
    int tgt = SEG_TOK + tl;
    int start = starts[tgt] + blkexcl[tgt >> 10];
    int cnt = cnts[tgt];
    const float* ybase = y + (size_t)b * (HD * WD * COUT);
    float4 num = make_float4(0.f, 0.f, 0.f, 0.f);
    float den = 0.f;
    for (int j = 0; j < cnt; ++j) {
        int gp = pidx[start + j];
        float lx = fminf(fmaxf(loc[2 * (size_t)gp], -1.f), 1.f);
        float ly = fminf(fmaxf(loc[2 * (size_t)gp + 1], -1.f), 1.f);
        float fx = fminf(fmaxf(0.5f * (lx + 1.f) * WD - 0.5f, 0.f), (float)(WD - 1));
        float fy = fminf(fmaxf(0.5f * (ly + 1.f) * HD - 0.5f, 0.f), (float)(HD - 1));
        float x0f = floorf(fx), y0f = floorf(fy);
        float wx = fx - x0f, wy = fy - y0f;
        int x0 = (int)x0f, y0 = (int)y0f;
        int x1 = min(x0 + 1, WD - 1), y1 = min(y0 + 1, HD - 1);
        float4 v00 = *(const float4*)(ybase + ((size_t)y0 * WD + x0) * COUT + lane * 4);
        float4 v01 = *(const float4*)(ybase + ((size_t)y0 * WD + x1) * COUT + lane * 4);
        float4 v10 = *(const float4*)(ybase + ((size_t)y1 * WD + x0) * COUT + lane * 4);
        float4 v11 = *(const float4*)(ybase + ((size_t)y1 * WD + x1) * COUT + lane * 4);
        float w00 = (1.f - wx) * (1.f - wy), w01 = wx * (1.f - wy);
        float w10 = (1.f - wx) * wy, w11 = wx * wy;
        float aw = aggw[gp];
        num.x += (w00 * v00.x + w01 * v01.x + w10 * v10.x + w11 * v11.x) * aw;
        num.y += (w00 * v00.y + w01 * v01.y + w10 * v10.y + w11 * v11.y) * aw;
        num.z += (w00 * v00.z + w01 * v01.z + w10 * v10.z + w11 * v11.z) * aw;
        num.w += (w00 * v00.w + w01 * v01.w + w10 * v10.w + w11 * v11.w) * aw;
        den += aw;
    }
    *(float4*)(num_out + (size_t)tl * COUT + lane * 4) = num;
    if (lane == 0) den1[tl] = den;
}

// tok = num/(den1+eps) + x @ skip_w^T   (in place over the num buffer = out_x region)
__global__ __launch_bounds__(256) void k_tok(const float* __restrict__ x,
                                             const float* __restrict__ swt,
                                             const float* __restrict__ den1,
                                             float* __restrict__ tok) {
    int t0 = blockIdx.x * 32;
    int tid = threadIdx.x;
    int nt = tid & 63, pt = tid >> 6;
    int n = nt * 4;
    __shared__ float xs[32 * CIN];
    for (int idx = tid; idx < 32 * 32; idx += 256) {
        int p = idx >> 5, c4 = idx & 31;
        *(float4*)(xs + p * CIN + c4 * 4) =
            *(const float4*)(x + ((size_t)(t0 + p)) * CIN + c4 * 4);
    }
    __syncthreads();
    float acc[4][8];
#pragma unroll
    for (int i = 0; i < 4; ++i)
#pragma unroll
        for (int j = 0; j < 8; ++j) acc[i][j] = 0.f;
#pragma unroll 4
    for (int c = 0; c < CIN; ++c) {
        float4 w4 = *(const float4*)(swt + (size_t)c * COUT + n);
#pragma unroll
        for (int j = 0; j < 8; ++j) {
            float a = xs[(pt * 8 + j) * CIN + c];
            acc[0][j] = fmaf(a, w4.x, acc[0][j]);
            acc[1][j] = fmaf(a, w4.y, acc[1][j]);
            acc[2][j] = fmaf(a, w4.z, acc[2][j]);
            acc[3][j] = fmaf(a, w4.w, acc[3][j]);
        }
    }
#pragma unroll
    for (int j = 0; j < 8; ++j) {
        int tkn = t0 + pt * 8 + j;
        float inv = 1.f / (den1[tkn] + EPS);
        float* pp = tok + (size_t)tkn * COUT + n;
        float4 v = *(float4*)pp;
        v.x = v.x * inv + acc[0][j];
        v.y = v.y * inv + acc[1][j];
        v.z = v.z * inv + acc[2][j];
        v.w = v.w * inv + acc[3][j];
        *(float4*)pp = v;
    }
}

__global__ void k_bnstats(const float* __restrict__ tok, float* __restrict__ bnsum,
                          float* __restrict__ bnsq) {
    int k = threadIdx.x;
    size_t t0 = (size_t)blockIdx.x * 256;
    float s = 0.f, sq = 0.f;
    for (int t = 0; t < 256; ++t) {
        float v = tok[(t0 + t) * COUT + k];
        s += v;
        sq = fmaf(v, v, sq);
    }
    atomicAdd(bnsum + k, s);
    atomicAdd(bnsq + k, sq);
}

// per-channel BN affine: a=gamma/sqrt(var+eps), bb=beta-mu*a; fold conf head
__global__ void k_bnparams(const float* __restrict__ bnsum, const float* __restrict__ bnsq,
                           const float* __restrict__ gamma, const float* __restrict__ beta,
                           const float* __restrict__ confw, const float* __restrict__ confb,
                           float* __restrict__ abuf, float* __restrict__ bbuf,
                           float* __restrict__ cwa, float* __restrict__ c0) {
    int k = threadIdx.x;
    const float cntv = (float)(BB * NTOK);
    float mu = bnsum[k] / cntv;
    float var = bnsq[k] / cntv - mu * mu;
    float a = gamma[k] * rsqrtf(var + BNEPS);
    float bbv = beta[k] - mu * a;
    abuf[k] = a;
    bbuf[k] = bbv;
    float cw = confw[k];
    cwa[k] = a * cw;
    __shared__ float red[256];
    red[k] = bbv * cw;
    __syncthreads();
    for (int s = 128; s > 0; s >>= 1) {
        if (k < s) red[k] += red[k + s];
        __syncthreads();
    }
    if (k == 0) c0[0] = red[0] + confb[0];
}

// conf = tokn @ conf_w^T + conf_b, folded:  dot(tok, cwa) + c0
__global__ void k_conf(const float* __restrict__ tok, const float* __restrict__ cwa,
                       const float* __restrict__ c0v, float* __restrict__ conf_out) {
    int tid = threadIdx.x;
    int tkn = blockIdx.x * 16 + (tid >> 4);
    int kc = (tid & 15) * 16;
    const float* row = tok + (size_t)tkn * COUT + kc;
    float s = 0.f;
#pragma unroll
    for (int i = 0; i < 16; i += 4) {
        float4 v = *(const float4*)(row + i);
        float4 w = *(const float4*)(cwa + kc + i);
        s += v.x * w.x + v.y * w.y + v.z * w.z + v.w * w.w;
    }
    for (int off = 8; off > 0; off >>= 1) s += __shfl_down(s, off, 16);
    if ((tid & 15) == 0) conf_out[tkn] = s + c0v[0];
}

// cluster as gather: per coarse cell, sum BN(tok)*w over its points; fused relu epilogue
__global__ __launch_bounds__(256) void k_gather_cluster(const float* __restrict__ tok,
                                                        const float* __restrict__ conf,
                                                        const float* __restrict__ abuf,
                                                        const float* __restrict__ bbuf,
                                                        const int* __restrict__ starts,
                                                        const int* __restrict__ blkexcl,
                                                        const int* __restrict__ cnts,
                                                        const int* __restrict__ pidx,
                                                        float* __restrict__ xdown,
                                                        float* __restrict__ den2) {
    int wv = threadIdx.x >> 6, lane = threadIdx.x & 63;  // 64 lanes x float4 = 256 ch
    int tl = blockIdx.x * 4 + wv;                        // over BB*NS
    int b = tl >> 12;
    int tgt = SEG_64 + tl;
    int start = starts[tgt] + blkexcl[tgt >> 10];
    int cnt = cnts[tgt];
    float4 a = *(const float4*)(abuf + lane * 4);
    float4 bb = *(const float4*)(bbuf + lane * 4);
    float4 num = make_float4(0.f, 0.f, 0.f, 0.f);
    float den = 0.f;
    for (int j = 0; j < cnt; ++j) {
        int ia = pidx[start + j];
        float w = expf(conf[(size_t)b * NTOK + ia]);
        float4 tv = *(const float4*)(tok + ((size_t)b * NTOK + ia) * COUT + lane * 4);
        num.x = fmaf(fmaf(a.x, tv.x, bb.x), w, num.x);
        num.y = fmaf(fmaf(a.y, tv.y, bb.y), w, num.y);
        num.z = fmaf(fmaf(a.z, tv.z, bb.z), w, num.z);
        num.w = fmaf(fmaf(a.w, tv.w, bb.w), w, num.w);
        den += w;
    }
    float inv = 1.f / (den + EPS);
    float4 o;
    o.x = fmaxf(num.x * inv, 0.f);
    o.y = fmaxf(num.y * inv, 0.f);
    o.z = fmaxf(num.z * inv, 0.f);
    o.w = fmaxf(num.w * inv, 0.f);
    *(float4*)(xdown + (size_t)tl * COUT + lane * 4) = o;
    if (lane == 0) den2[tl] = den;
}

// agg_weight_down numerator + per-batch max (positive floats -> uint atomicMax)
__global__ void k_awd1(const float* __restrict__ conf, const float* __restrict__ den2,
                       const int* __restrict__ idx_agg, const int* __restrict__ cell64,
                       const float* __restrict__ aggw, float* __restrict__ awdt,
                       float* __restrict__ idx_out_f, unsigned int* __restrict__ maxw) {
    int b = blockIdx.x >> 6;
    int chunk = blockIdx.x & 63;
    int base = b * NP + chunk * 1024;
    float lmax = 0.f;
    for (int t = threadIdx.x; t < 1024; t += 256) {
        int gp = base + t;
        int ia = idx_agg[gp];
        int cell = cell64[gp];
        float w = expf(conf[(size_t)b * NTOK + ia]);
        float wt = w / (den2[(size_t)b * NS + cell] + EPS);
        float tv = aggw[gp] * wt;
        awdt[gp] = tv;
        idx_out_f[gp] = (float)cell;
        lmax = fmaxf(lmax, tv);
    }
    __shared__ float red[256];
    red[threadIdx.x] = lmax;
    __syncthreads();
    for (int s = 128; s > 0; s >>= 1) {
        if (threadIdx.x < s) red[threadIdx.x] = fmaxf(red[threadIdx.x], red[threadIdx.x + s]);
        __syncthreads();
    }
    if (threadIdx.x == 0) atomicMax(maxw + b, __float_as_uint(red[0]));
}

__global__ void k_awd2(const float* __restrict__ awdt, const unsigned int* __restrict__ maxw,
                       float* __restrict__ awd_out) {
    int i = blockIdx.x * 256 + threadIdx.x;  // over BB*NP
    int b = i >> 16;
    awd_out[i] = awdt[i] / __uint_as_float(maxw[b]);
}

// overwrite tok (out_x region) with relu(tokn) in place
__global__ void k_relutok(float* __restrict__ tok, const float* __restrict__ abuf,
                          const float* __restrict__ bbuf) {
    size_t i = (size_t)blockIdx.x * 256 + threadIdx.x;  // float4 index
    int k4 = (int)(i & 63) * 4;
    float4 a = *(const float4*)(abuf + k4);
    float4 bb = *(const float4*)(bbuf + k4);
    float4 v = ((float4*)tok)[i];
    v.x = fmaxf(fmaf(a.x, v.x, bb.x), 0.f);
    v.y = fmaxf(fmaf(a.y, v.y, bb.y), 0.f);
    v.z = fmaxf(fmaf(a.z, v.z, bb.z), 0.f);
    v.w = fmaxf(fmaf(a.w, v.w, bb.w), 0.f);
    ((float4*)tok)[i] = v;
}

extern "C" void kernel_launch(void* const* d_in, const int* in_sizes, int n_in,
                              void* d_out, int out_size, void* d_ws, size_t ws_size,
                              hipStream_t stream) {
    const float* x        = (const float*)d_in[0];
    const float* loc      = (const float*)d_in[1];
    const int*   idx_agg  = (const int*)d_in[2];
    const float* aggw     = (const float*)d_in[3];
    const float* conv_w   = (const float*)d_in[4];
    const float* conv_b   = (const float*)d_in[5];
    const float* skip_w   = (const float*)d_in[6];
    const float* bn_gamma = (const float*)d_in[7];
    const float* bn_beta  = (const float*)d_in[8];
    const float* conf_w   = (const float*)d_in[9];
    const float* conf_b   = (const float*)d_in[10];

    float* ws      = (float*)d_ws;
    float* bnsum   = ws + BNSUM_OFF;
    float* bnsq    = ws + BNSQ_OFF;
    unsigned int* maxw = (unsigned int*)(ws + MAXW_OFF);
    int*   cnts    = (int*)(ws + CNTS_OFF);
    int*   curs    = (int*)(ws + CURS_OFF);
    float* ybuf    = ws + YBUF_OFF;
    unsigned short* xmapn = (unsigned short*)(ws + XMAPN_OFF);
    unsigned short* wfrag = (unsigned short*)(ws + WFRAG_OFF);
    float* awdt    = ws + AWDT_OFF;
    float* abuf    = ws + ABUF_OFF;
    float* bbuf    = ws + BBUF_OFF;
    float* cwa     = ws + CWA_OFF;
    float* c0      = ws + C0_OFF;
    float* swt     = ws + SWT_OFF;
    int*   cell256 = (int*)(ws + CELL256_OFF);
    int*   cell64  = (int*)(ws + CELL64_OFF);
    float* den1    = ws + DEN1_OFF;
    float* den2    = ws + DEN2_OFF;
    int*   starts  = (int*)(ws + STARTS_OFF);
    int*   blksum  = (int*)(ws + BLKSUM_OFF);
    int*   blkexcl = (int*)(ws + BLKEXCL_OFF);
    int*   pidx    = (int*)(ws + PIDX_OFF);

    float* out       = (float*)d_out;
    float* out_xdown = out;                                    // [4,4096,256]
    float* out_x     = out + (size_t)BB * NS * COUT;           // [4,16384,256] (num -> tok -> relu(tokn))
    float* out_conf  = out_x + (size_t)BB * NTOK * COUT;       // [4,16384,1]
    float* out_awd   = out_conf + (size_t)BB * NTOK;           // [4,65536,1]
    float* out_idx   = out_awd + (size_t)BB * NP;              // [4,65536] written as float

    // zero the small accumulator region (ws is poisoned 0xAA every call)
    hipMemsetAsync(d_ws, 0, ZERO_FLOATS * sizeof(float), stream);

    k_cells<<<BB * NP / 256, 256, 0, stream>>>(loc, cell256, cell64);
    k_transpose_skip<<<(COUT * CIN) / 256, 256, 0, stream>>>(skip_w, swt);
    k_wfrag<<<9 * 4 * 16 * 512 / 256, 256, 0, stream>>>(conv_w, wfrag);
    k_hist<<<BB * NP / 256, 256, 0, stream>>>(cell256, idx_agg, cell64, cnts);
    k_scan1<<<NSEG / 1024, 256, 0, stream>>>(cnts, starts, blksum);
    k_scan2<<<1, 512, 0, stream>>>(blksum, blkexcl);
    k_fill<<<BB * NP / 256, 256, 0, stream>>>(cell256, idx_agg, cell64, starts,
                                              blkexcl, curs, pidx);
    k_gather_map<<<BB * NP / 8, 256, 0, stream>>>(x, starts, blkexcl, cnts, pidx, xmapn);
    k_convmf<<<BB * HD * 2, 256, 0, stream>>>(xmapn, wfrag, conv_b, ybuf);
    k_gather_tok<<<BB * NTOK / 4, 256, 0, stream>>>(ybuf, loc, aggw, starts, blkexcl,
                                                    cnts, pidx, out_x, den1);
    k_tok<<<BB * NTOK / 32, 256, 0, stream>>>(x, swt, den1, out_x);
    k_bnstats<<<BB * NTOK / 256, 256, 0, stream>>>(out_x, bnsum, bnsq);
    k_bnparams<<<1, 256, 0, stream>>>(bnsum, bnsq, bn_gamma, bn_beta, conf_w, conf_b,
                                      abuf, bbuf, cwa, c0);
    k_conf<<<BB * NTOK / 16, 256, 0, stream>>>(out_x, cwa, c0, out_conf);
    k_gather_cluster<<<BB * NS / 4, 256, 0, stream>>>(out_x, out_conf, abuf, bbuf,
                                                      starts, blkexcl, cnts, pidx,
                                                      out_xdown, den2);
    k_awd1<<<BB * 64, 256, 0, stream>>>(out_conf, den2, idx_agg, cell64, aggw,
                                        awdt, out_idx, maxw);
    k_awd2<<<BB * NP / 256, 256, 0, stream>>>(awdt, maxw, out_awd);
    k_relutok<<<BB * NTOK * COUT / 4 / 256, 256, 0, stream>>>(out_x, abuf, bbuf);
}

// Round 4
// 535.930 us; speedup vs baseline: 3.1169x; 1.1655x over previous
//
#include <hip/hip_runtime.h>
#include <hip/hip_bf16.h>
#include <math.h>

// Problem constants (fixed by setup_inputs)
#define BB    4
#define NTOK  16384
#define CIN   128
#define COUT  256
#define HM    256
#define WM    256
#define NP    65536      // HM*WM original points per batch
#define HD    128
#define WD    128
#define HC    64
#define WC    64
#define NS    4096       // HC*WC
#define EPS   1e-6f
#define BNEPS 1e-5f

// CSR segment bases (concatenated target domains)
#define SEG_TOK  (BB * NP)                  // 262144
#define SEG_64   (SEG_TOK + BB * NTOK)      // 327680
#define NSEG     (SEG_64 + BB * NS)         // 344064 = 336 * 1024

typedef __attribute__((ext_vector_type(8))) short bfrag8;
typedef __attribute__((ext_vector_type(4))) float ffrag4;

// ---------------- workspace layout (floats) ----------------
// zeroed block first (one small memset), then non-zeroed scratch
static constexpr size_t BNSUM_OFF  = 0;                                   // 256
static constexpr size_t BNSQ_OFF   = BNSUM_OFF + 256;                     // 256
static constexpr size_t MAXW_OFF   = BNSQ_OFF + 256;                      // 4 (pad 256)
static constexpr size_t CNTS_OFF   = MAXW_OFF + 256;                      // NSEG ints
static constexpr size_t CURS_OFF   = CNTS_OFF + NSEG;                     // NSEG ints
static constexpr size_t ZERO_FLOATS = CURS_OFF + NSEG;
// non-zeroed:
static constexpr size_t YBUF_OFF   = (ZERO_FLOATS + 255) & ~(size_t)255;  // BB*HD*WD*COUT bf16 -> /2 floats
static constexpr size_t XMAPN_OFF  = YBUF_OFF + (size_t)BB * HD * WD * COUT / 2; // BB*NP*CIN bf16 -> /2
static constexpr size_t XBF_OFF    = XMAPN_OFF + (size_t)BB * NP * CIN / 2;  // BB*NTOK*CIN bf16 -> /2
static constexpr size_t TOKB_OFF   = XBF_OFF + (size_t)BB * NTOK * CIN / 2;  // BB*NTOK*COUT bf16 -> /2
static constexpr size_t WFRAG_OFF  = TOKB_OFF + (size_t)BB * NTOK * COUT / 2; // 9*4*16*512 bf16 -> /2
static constexpr size_t SFRAG_OFF  = WFRAG_OFF + (size_t)9 * 4 * 16 * 512 / 2; // 4*16*512 bf16 -> /2
static constexpr size_t WEXP_OFF   = SFRAG_OFF + (size_t)4 * 16 * 512 / 2;  // BB*NTOK
static constexpr size_t AWDT_OFF   = WEXP_OFF + (size_t)BB * NTOK;        // BB*NP
static constexpr size_t ABUF_OFF   = AWDT_OFF + (size_t)BB * NP;          // 256
static constexpr size_t BBUF_OFF   = ABUF_OFF + 256;                      // 256
static constexpr size_t CWA_OFF    = BBUF_OFF + 256;                      // 256
static constexpr size_t C0_OFF     = CWA_OFF + 256;                       // 256
static constexpr size_t CELL256_OFF = C0_OFF + 256;                       // BB*NP ints
static constexpr size_t CELL64_OFF  = CELL256_OFF + (size_t)BB * NP;      // BB*NP ints
static constexpr size_t DEN1_OFF   = CELL64_OFF + (size_t)BB * NP;        // BB*NTOK
static constexpr size_t DEN2_OFF   = DEN1_OFF + (size_t)BB * NTOK;        // BB*NS
static constexpr size_t STARTS_OFF = DEN2_OFF + (size_t)BB * NS;          // NSEG ints
static constexpr size_t BLKSUM_OFF = STARTS_OFF + NSEG;                   // 512 ints
static constexpr size_t BLKEXCL_OFF = BLKSUM_OFF + 512;                   // 512 ints
static constexpr size_t PIDX_OFF   = BLKEXCL_OFF + 512;                   // 3*BB*NP ints

// ---------------- helpers ----------------

__device__ __forceinline__ unsigned short f2bf(float f) {
    unsigned int u = __float_as_uint(f);
    return (unsigned short)((u + 0x7FFFu + ((u >> 16) & 1u)) >> 16);
}
__device__ __forceinline__ float bf2f(unsigned short u) {
    return __uint_as_float((unsigned int)u << 16);
}

// ---------------- kernels ----------------

// grid cell indices for both grids (matches jnp.round = RNE via rintf)
__global__ void k_cells(const float* __restrict__ loc, int* __restrict__ cell256,
                        int* __restrict__ cell64) {
    int i = blockIdx.x * 256 + threadIdx.x;   // over BB*NP
    float lx = fminf(fmaxf(loc[2 * (size_t)i], -1.f), 1.f);
    float ly = fminf(fmaxf(loc[2 * (size_t)i + 1], -1.f), 1.f);
    int px = (int)rintf(0.5f * (lx + 1.f) * WM - 0.5f);
    px = min(max(px, 0), WM - 1);
    int py = (int)rintf(0.5f * (ly + 1.f) * HM - 0.5f);
    py = min(max(py, 0), HM - 1);
    cell256[i] = py * WM + px;
    int qx = (int)rintf(0.5f * (lx + 1.f) * WC - 0.5f);
    qx = min(max(qx, 0), WC - 1);
    int qy = (int)rintf(0.5f * (ly + 1.f) * HC - 0.5f);
    qy = min(max(qy, 0), HC - 1);
    cell64[i] = qy * WC + qx;
}

// cast x to bf16 once (random-gather source for k_gather_map)
__global__ void k_xcast(const float* __restrict__ x, unsigned short* __restrict__ xbf) {
    size_t i = (size_t)blockIdx.x * 256 + threadIdx.x;  // float4 groups
    float4 v = ((const float4*)x)[i];
    ushort4 o;
    o.x = f2bf(v.x); o.y = f2bf(v.y); o.z = f2bf(v.z); o.w = f2bf(v.w);
    ((ushort4*)xbf)[i] = o;
}

// histogram of all three target domains (concatenated)
__global__ void k_hist(const int* __restrict__ cell256, const int* __restrict__ idx_agg,
                       const int* __restrict__ cell64, int* __restrict__ cnts) {
    int gp = blockIdx.x * 256 + threadIdx.x;  // over BB*NP
    int b = gp >> 16;
    atomicAdd(&cnts[b * NP + cell256[gp]], 1);
    atomicAdd(&cnts[SEG_TOK + b * NTOK + idx_agg[gp]], 1);
    atomicAdd(&cnts[SEG_64 + b * NS + cell64[gp]], 1);
}

// 2-level exclusive scan over NSEG = 336*1024 counters
__global__ __launch_bounds__(256) void k_scan1(const int* __restrict__ cnts,
                                               int* __restrict__ starts,
                                               int* __restrict__ blksum) {
    int t = threadIdx.x;
    int base = blockIdx.x * 1024 + t * 4;
    int4 v = *(const int4*)(cnts + base);
    int tsum = v.x + v.y + v.z + v.w;
    __shared__ int s[256];
    s[t] = tsum;
    __syncthreads();
    for (int off = 1; off < 256; off <<= 1) {
        int add = (t >= off) ? s[t - off] : 0;
        __syncthreads();
        s[t] += add;
        __syncthreads();
    }
    int excl = s[t] - tsum;
    int4 o;
    o.x = excl; o.y = excl + v.x; o.z = o.y + v.y; o.w = o.z + v.z;
    *(int4*)(starts + base) = o;
    if (t == 255) blksum[blockIdx.x] = s[255];
}

__global__ __launch_bounds__(512) void k_scan2(const int* __restrict__ blksum,
                                               int* __restrict__ blkexcl) {
    int t = threadIdx.x;
    __shared__ int s[512];
    int v = (t < 336) ? blksum[t] : 0;
    s[t] = v;
    __syncthreads();
    for (int off = 1; off < 512; off <<= 1) {
        int add = (t >= off) ? s[t - off] : 0;
        __syncthreads();
        s[t] += add;
        __syncthreads();
    }
    if (t < 336) blkexcl[t] = s[t] - v;
}

// fill CSR pools: map stores resolved token id, tok stores point id, cell64 stores token id
__global__ void k_fill(const int* __restrict__ cell256, const int* __restrict__ idx_agg,
                       const int* __restrict__ cell64, const int* __restrict__ starts,
                       const int* __restrict__ blkexcl, int* __restrict__ curs,
                       int* __restrict__ pidx) {
    int gp = blockIdx.x * 256 + threadIdx.x;  // over BB*NP
    int b = gp >> 16;
    int ia = idx_agg[gp];
    int t1 = b * NP + cell256[gp];
    int p1 = starts[t1] + blkexcl[t1 >> 10] + atomicAdd(&curs[t1], 1);
    pidx[p1] = ia;
    int t2 = SEG_TOK + b * NTOK + ia;
    int p2 = starts[t2] + blkexcl[t2 >> 10] + atomicAdd(&curs[t2], 1);
    pidx[p2] = gp;
    int t3 = SEG_64 + b * NS + cell64[gp];
    int p3 = starts[t3] + blkexcl[t3 >> 10] + atomicAdd(&curs[t3], 1);
    pidx[p3] = ia;
}

// token2map as gather: per map cell, sum bf16 token rows, normalize, write bf16
__global__ __launch_bounds__(256) void k_gather_map(const unsigned short* __restrict__ xbf,
                                                    const int* __restrict__ starts,
                                                    const int* __restrict__ blkexcl,
                                                    const int* __restrict__ cnts,
                                                    const int* __restrict__ pidx,
                                                    unsigned short* __restrict__ xmapn) {
    int tgt = blockIdx.x * 8 + (threadIdx.x >> 5);  // over BB*NP
    int lane = threadIdx.x & 31;                    // 32 lanes x 4ch = 128 ch
    int b = tgt >> 16;
    int start = starts[tgt] + blkexcl[tgt >> 10];
    int cnt = cnts[tgt];
    float4 acc = make_float4(0.f, 0.f, 0.f, 0.f);
    for (int j = 0; j < cnt; ++j) {
        int tk = pidx[start + j];
        ushort4 u = *(const ushort4*)(xbf + ((size_t)b * NTOK + tk) * CIN + lane * 4);
        acc.x += bf2f(u.x); acc.y += bf2f(u.y); acc.z += bf2f(u.z); acc.w += bf2f(u.w);
    }
    float inv = 1.0f / ((float)cnt + EPS);
    ushort4 o;
    o.x = f2bf(acc.x * inv);
    o.y = f2bf(acc.y * inv);
    o.z = f2bf(acc.z * inv);
    o.w = f2bf(acc.w * inv);
    *(ushort4*)(xmapn + (size_t)tgt * CIN + lane * 4) = o;
}

// pre-swizzle conv weights into MFMA 16x16x32 B-fragment lane layout
__global__ void k_wfrag(const float* __restrict__ cw, unsigned short* __restrict__ wfrag) {
    int i = blockIdx.x * 256 + threadIdx.x;  // over 9*4*16*512
    int j = i & 7;
    int lane = (i >> 3) & 63;
    int nt = (i >> 9) & 15;
    int kc = (i >> 13) & 3;
    int khw = i >> 15;
    int c = kc * 32 + ((lane >> 4) << 3) + j;
    int n = nt * 16 + (lane & 15);
    wfrag[i] = f2bf(cw[((size_t)khw * CIN + c) * COUT + n]);
}

// pre-swizzle skip weights (COUT x CIN, row-major) into same B-fragment layout
__global__ void k_sfrag(const float* __restrict__ sw, unsigned short* __restrict__ sfrag) {
    int i = blockIdx.x * 256 + threadIdx.x;  // over 4*16*512
    int j = i & 7;
    int lane = (i >> 3) & 63;
    int nt = (i >> 9) & 15;
    int kc = i >> 13;
    int c = kc * 32 + ((lane >> 4) << 3) + j;
    int n = nt * 16 + (lane & 15);
    sfrag[i] = f2bf(sw[(size_t)n * CIN + c]);
}

// 3x3 stride-2 pad-1 conv as implicit GEMM on bf16 MFMA 16x16x32; bf16 output.
__global__ __launch_bounds__(256) void k_convmf(const unsigned short* __restrict__ xmapn,
                                                const unsigned short* __restrict__ wfrag,
                                                const float* __restrict__ cb,
                                                unsigned short* __restrict__ y) {
    int bz = blockIdx.x;
    int ow0 = (bz & 1) * 64;
    int oh = (bz >> 1) & (HD - 1);
    int b = bz >> 8;
    int tid = threadIdx.x;
    int w = tid >> 6, lane = tid & 63;
    int n0 = w * 64;

    __shared__ unsigned short s_even[65 * 136];
    __shared__ unsigned short s_odd[64 * 136];

    ffrag4 acc[4][4];
#pragma unroll
    for (int mt = 0; mt < 4; ++mt)
#pragma unroll
        for (int nt = 0; nt < 4; ++nt) {
            ffrag4 z = {0.f, 0.f, 0.f, 0.f};
            acc[mt][nt] = z;
        }

    int iw0 = 2 * ow0 - 1;
    int lm = lane & 15;
    int lq = lane >> 4;
    int cbase = lq << 3;

    for (int kh = 0; kh < 3; ++kh) {
        int ih = 2 * oh - 1 + kh;
        __syncthreads();
        {
            const unsigned short* rowb =
                xmapn + ((size_t)b * NP + (size_t)ih * WM) * CIN;
            bool ihok = (ih >= 0 && ih < HM);
            for (int idx = tid; idx < 129 * 16; idx += 256) {
                int pix = idx >> 4;
                int c8 = (idx & 15) * 8;
                int iw = iw0 + pix;
                uint4 v = make_uint4(0u, 0u, 0u, 0u);
                if (ihok && iw >= 0 && iw < WM)
                    v = *(const uint4*)(rowb + (size_t)iw * CIN + c8);
                unsigned short* dst = (pix & 1)
                    ? &s_odd[(size_t)((pix - 1) >> 1) * 136 + c8]
                    : &s_even[(size_t)(pix >> 1) * 136 + c8];
                *(uint4*)dst = v;
            }
        }
        __syncthreads();
#pragma unroll
        for (int kw = 0; kw < 3; ++kw) {
            int khw = kh * 3 + kw;
#pragma unroll
            for (int kc = 0; kc < 4; ++kc) {
                int c = kc * 32 + cbase;
                bfrag8 af[4];
#pragma unroll
                for (int mt = 0; mt < 4; ++mt) {
                    int m = mt * 16 + lm;
                    const unsigned short* src;
                    if (kw == 1)      src = &s_odd[(size_t)m * 136 + c];
                    else if (kw == 0) src = &s_even[(size_t)m * 136 + c];
                    else              src = &s_even[(size_t)(m + 1) * 136 + c];
                    af[mt] = *(const bfrag8*)(const void*)src;
                }
                const unsigned short* wb =
                    wfrag + ((size_t)((khw * 4 + kc) * 16) + w * 4) * 512 + lane * 8;
#pragma unroll
                for (int nt = 0; nt < 4; ++nt) {
                    bfrag8 bf = *(const bfrag8*)(const void*)(wb + (size_t)nt * 512);
#pragma unroll
                    for (int mt = 0; mt < 4; ++mt)
                        acc[mt][nt] = __builtin_amdgcn_mfma_f32_16x16x32_bf16(
                            af[mt], bf, acc[mt][nt], 0, 0, 0);
                }
            }
        }
    }

    unsigned short* yb = y + (((size_t)b * HD + oh) * WD + ow0) * COUT;
#pragma unroll
    for (int nt = 0; nt < 4; ++nt) {
        int n = n0 + nt * 16 + lm;
        float bias = cb[n];
#pragma unroll
        for (int mt = 0; mt < 4; ++mt) {
#pragma unroll
            for (int r = 0; r < 4; ++r) {
                int m = mt * 16 + lq * 4 + r;
                yb[(size_t)m * COUT + n] = f2bf(acc[mt][nt][r] + bias);
            }
        }
    }
}

// map2token as gather: per token, bilinear-sample its points from bf16 y, direct write
__global__ __launch_bounds__(256) void k_gather_tok(const unsigned short* __restrict__ y,
                                                    const float* __restrict__ loc,
                                                    const float* __restrict__ aggw,
                                                    const int* __restrict__ starts,
                                                    const int* __restrict__ blkexcl,
                                                    const int* __restrict__ cnts,
                                                    const int* __restrict__ pidx,
                                                    float* __restrict__ num_out,
                                                    float* __restrict__ den1) {
    int wv = threadIdx.x >> 6, lane = threadIdx.x & 63;  // 64 lanes x 4ch = 256 ch
    int tl = blockIdx.x * 4 + wv;                        // over BB*NTOK
    int b = tl >> 14;
    int tgt = SEG_TOK + tl;
    int start = starts[tgt] + blkexcl[tgt >> 10];
    int cnt = cnts[tgt];
    const unsigned short* ybase = y + (size_t)b * (HD * WD * COUT);
    float4 num = make_float4(0.f, 0.f, 0.f, 0.f);
    float den = 0.f;
    for (int j = 0; j < cnt; ++j) {
        int gp = pidx[start + j];
        float lx = fminf(fmaxf(loc[2 * (size_t)gp], -1.f), 1.f);
        float ly = fminf(fmaxf(loc[2 * (size_t)gp + 1], -1.f), 1.f);
        float fx = fminf(fmaxf(0.5f * (lx + 1.f) * WD - 0.5f, 0.f), (float)(WD - 1));
        float fy = fminf(fmaxf(0.5f * (ly + 1.f) * HD - 0.5f, 0.f), (float)(HD - 1));
        float x0f = floorf(fx), y0f = floorf(fy);
        float wx = fx - x0f, wy = fy - y0f;
        int x0 = (int)x0f, y0 = (int)y0f;
        int x1 = min(x0 + 1, WD - 1), y1 = min(y0 + 1, HD - 1);
        ushort4 u00 = *(const ushort4*)(ybase + ((size_t)y0 * WD + x0) * COUT + lane * 4);
        ushort4 u01 = *(const ushort4*)(ybase + ((size_t)y0 * WD + x1) * COUT + lane * 4);
        ushort4 u10 = *(const ushort4*)(ybase + ((size_t)y1 * WD + x0) * COUT + lane * 4);
        ushort4 u11 = *(const ushort4*)(ybase + ((size_t)y1 * WD + x1) * COUT + lane * 4);
        float w00 = (1.f - wx) * (1.f - wy), w01 = wx * (1.f - wy);
        float w10 = (1.f - wx) * wy, w11 = wx * wy;
        float aw = aggw[gp];
        num.x += (w00 * bf2f(u00.x) + w01 * bf2f(u01.x) + w10 * bf2f(u10.x) + w11 * bf2f(u11.x)) * aw;
        num.y += (w00 * bf2f(u00.y) + w01 * bf2f(u01.y) + w10 * bf2f(u10.y) + w11 * bf2f(u11.y)) * aw;
        num.z += (w00 * bf2f(u00.z) + w01 * bf2f(u01.z) + w10 * bf2f(u10.z) + w11 * bf2f(u11.z)) * aw;
        num.w += (w00 * bf2f(u00.w) + w01 * bf2f(u01.w) + w10 * bf2f(u10.w) + w11 * bf2f(u11.w)) * aw;
        den += aw;
    }
    *(float4*)(num_out + (size_t)tl * COUT + lane * 4) = num;
    if (lane == 0) den1[tl] = den;
}

// tok = num/(den1+eps) + x @ skip_w^T via MFMA (in place over out_x region)
__global__ __launch_bounds__(256) void k_tokmf(const unsigned short* __restrict__ xbf,
                                               const unsigned short* __restrict__ sfrag,
                                               const float* __restrict__ den1,
                                               float* __restrict__ tok) {
    int t0 = blockIdx.x * 64;   // grid = BB*NTOK/64
    int tid = threadIdx.x;
    int w = tid >> 6, lane = tid & 63;
    int n0 = w * 64;
    int lm = lane & 15, lq = lane >> 4;

    __shared__ unsigned short s_x[64 * 136];
    const unsigned short* xb = xbf + (size_t)t0 * CIN;
    for (int idx = tid; idx < 64 * 16; idx += 256) {
        int row = idx >> 4, c8 = (idx & 15) * 8;
        *(uint4*)&s_x[(size_t)row * 136 + c8] = *(const uint4*)(xb + (size_t)row * CIN + c8);
    }
    __syncthreads();

    ffrag4 acc[4][4];
#pragma unroll
    for (int mt = 0; mt < 4; ++mt)
#pragma unroll
        for (int nt = 0; nt < 4; ++nt) {
            ffrag4 z = {0.f, 0.f, 0.f, 0.f};
            acc[mt][nt] = z;
        }

#pragma unroll
    for (int kc = 0; kc < 4; ++kc) {
        int c = kc * 32 + lq * 8;
        bfrag8 af[4];
#pragma unroll
        for (int mt = 0; mt < 4; ++mt)
            af[mt] = *(const bfrag8*)(const void*)&s_x[(size_t)(mt * 16 + lm) * 136 + c];
        const unsigned short* sb = sfrag + ((size_t)(kc * 16) + w * 4) * 512 + lane * 8;
#pragma unroll
        for (int nt = 0; nt < 4; ++nt) {
            bfrag8 bf = *(const bfrag8*)(const void*)(sb + (size_t)nt * 512);
#pragma unroll
            for (int mt = 0; mt < 4; ++mt)
                acc[mt][nt] = __builtin_amdgcn_mfma_f32_16x16x32_bf16(
                    af[mt], bf, acc[mt][nt], 0, 0, 0);
        }
    }

#pragma unroll
    for (int mt = 0; mt < 4; ++mt) {
#pragma unroll
        for (int r = 0; r < 4; ++r) {
            int tkn = t0 + mt * 16 + lq * 4 + r;
            float inv = 1.f / (den1[tkn] + EPS);
#pragma unroll
            for (int nt = 0; nt < 4; ++nt) {
                int n = n0 + nt * 16 + lm;
                size_t a = (size_t)tkn * COUT + n;
                tok[a] = tok[a] * inv + acc[mt][nt][r];
            }
        }
    }
}

__global__ void k_bnstats(const float* __restrict__ tok, float* __restrict__ bnsum,
                          float* __restrict__ bnsq) {
    int k = threadIdx.x;
    size_t t0 = (size_t)blockIdx.x * 256;
    float s = 0.f, sq = 0.f;
    for (int t = 0; t < 256; ++t) {
        float v = tok[(t0 + t) * COUT + k];
        s += v;
        sq = fmaf(v, v, sq);
    }
    atomicAdd(bnsum + k, s);
    atomicAdd(bnsq + k, sq);
}

// per-channel BN affine: a=gamma/sqrt(var+eps), bb=beta-mu*a; fold conf head
__global__ void k_bnparams(const float* __restrict__ bnsum, const float* __restrict__ bnsq,
                           const float* __restrict__ gamma, const float* __restrict__ beta,
                           const float* __restrict__ confw, const float* __restrict__ confb,
                           float* __restrict__ abuf, float* __restrict__ bbuf,
                           float* __restrict__ cwa, float* __restrict__ c0) {
    int k = threadIdx.x;
    const float cntv = (float)(BB * NTOK);
    float mu = bnsum[k] / cntv;
    float var = bnsq[k] / cntv - mu * mu;
    float a = gamma[k] * rsqrtf(var + BNEPS);
    float bbv = beta[k] - mu * a;
    abuf[k] = a;
    bbuf[k] = bbv;
    float cw = confw[k];
    cwa[k] = a * cw;
    __shared__ float red[256];
    red[k] = bbv * cw;
    __syncthreads();
    for (int s = 128; s > 0; s >>= 1) {
        if (k < s) red[k] += red[k + s];
        __syncthreads();
    }
    if (k == 0) c0[0] = red[0] + confb[0];
}

// conf = dot(tok, cwa) + c0; also emit tokn bf16 (tokb) and exp(conf) (wexp)
__global__ void k_conf(const float* __restrict__ tok, const float* __restrict__ cwa,
                       const float* __restrict__ c0v, const float* __restrict__ abuf,
                       const float* __restrict__ bbuf, float* __restrict__ conf_out,
                       unsigned short* __restrict__ tokb, float* __restrict__ wexp) {
    int tid = threadIdx.x;
    int tkn = blockIdx.x * 16 + (tid >> 4);
    int kc = (tid & 15) * 16;
    const float* row = tok + (size_t)tkn * COUT + kc;
    unsigned short* tb = tokb + (size_t)tkn * COUT + kc;
    float s = 0.f;
#pragma unroll
    for (int i = 0; i < 16; i += 4) {
        float4 v = *(const float4*)(row + i);
        float4 w = *(const float4*)(cwa + kc + i);
        float4 a = *(const float4*)(abuf + kc + i);
        float4 bb = *(const float4*)(bbuf + kc + i);
        s += v.x * w.x + v.y * w.y + v.z * w.z + v.w * w.w;
        ushort4 o;
        o.x = f2bf(fmaf(a.x, v.x, bb.x));
        o.y = f2bf(fmaf(a.y, v.y, bb.y));
        o.z = f2bf(fmaf(a.z, v.z, bb.z));
        o.w = f2bf(fmaf(a.w, v.w, bb.w));
        *(ushort4*)(tb + i) = o;
    }
    for (int off = 8; off > 0; off >>= 1) s += __shfl_down(s, off, 16);
    if ((tid & 15) == 0) {
        float cv = s + c0v[0];
        conf_out[tkn] = cv;
        wexp[tkn] = expf(cv);
    }
}

// cluster as gather over bf16 tokn rows + precomputed exp weights; fused relu epilogue
__global__ __launch_bounds__(256) void k_gather_cluster(const unsigned short* __restrict__ tokb,
                                                        const float* __restrict__ wexp,
                                                        const int* __restrict__ starts,
                                                        const int* __restrict__ blkexcl,
                                                        const int* __restrict__ cnts,
                                                        const int* __restrict__ pidx,
                                                        float* __restrict__ xdown,
                                                        float* __restrict__ den2) {
    int wv = threadIdx.x >> 6, lane = threadIdx.x & 63;  // 64 lanes x 4ch = 256 ch
    int tl = blockIdx.x * 4 + wv;                        // over BB*NS
    int b = tl >> 12;
    int tgt = SEG_64 + tl;
    int start = starts[tgt] + blkexcl[tgt >> 10];
    int cnt = cnts[tgt];
    float4 num = make_float4(0.f, 0.f, 0.f, 0.f);
    float den = 0.f;
    for (int j = 0; j < cnt; ++j) {
        int ia = pidx[start + j];
        float w = wexp[(size_t)b * NTOK + ia];
        ushort4 u = *(const ushort4*)(tokb + ((size_t)b * NTOK + ia) * COUT + lane * 4);
        num.x = fmaf(bf2f(u.x), w, num.x);
        num.y = fmaf(bf2f(u.y), w, num.y);
        num.z = fmaf(bf2f(u.z), w, num.z);
        num.w = fmaf(bf2f(u.w), w, num.w);
        den += w;
    }
    float inv = 1.f / (den + EPS);
    float4 o;
    o.x = fmaxf(num.x * inv, 0.f);
    o.y = fmaxf(num.y * inv, 0.f);
    o.z = fmaxf(num.z * inv, 0.f);
    o.w = fmaxf(num.w * inv, 0.f);
    *(float4*)(xdown + (size_t)tl * COUT + lane * 4) = o;
    if (lane == 0) den2[tl] = den;
}

// agg_weight_down numerator + per-batch max (positive floats -> uint atomicMax)
__global__ void k_awd1(const float* __restrict__ wexp, const float* __restrict__ den2,
                       const int* __restrict__ idx_agg, const int* __restrict__ cell64,
                       const float* __restrict__ aggw, float* __restrict__ awdt,
                       float* __restrict__ idx_out_f, unsigned int* __restrict__ maxw) {
    int b = blockIdx.x >> 6;
    int chunk = blockIdx.x & 63;
    int base = b * NP + chunk * 1024;
    float lmax = 0.f;
    for (int t = threadIdx.x; t < 1024; t += 256) {
        int gp = base + t;
        int ia = idx_agg[gp];
        int cell = cell64[gp];
        float w = wexp[(size_t)b * NTOK + ia];
        float wt = w / (den2[(size_t)b * NS + cell] + EPS);
        float tv = aggw[gp] * wt;
        awdt[gp] = tv;
        idx_out_f[gp] = (float)cell;
        lmax = fmaxf(lmax, tv);
    }
    __shared__ float red[256];
    red[threadIdx.x] = lmax;
    __syncthreads();
    for (int s = 128; s > 0; s >>= 1) {
        if (threadIdx.x < s) red[threadIdx.x] = fmaxf(red[threadIdx.x], red[threadIdx.x + s]);
        __syncthreads();
    }
    if (threadIdx.x == 0) atomicMax(maxw + b, __float_as_uint(red[0]));
}

__global__ void k_awd2(const float* __restrict__ awdt, const unsigned int* __restrict__ maxw,
                       float* __restrict__ awd_out) {
    int i = blockIdx.x * 256 + threadIdx.x;  // over BB*NP
    int b = i >> 16;
    awd_out[i] = awdt[i] / __uint_as_float(maxw[b]);
}

// overwrite tok (out_x region) with relu(tokn) in place
__global__ void k_relutok(float* __restrict__ tok, const float* __restrict__ abuf,
                          const float* __restrict__ bbuf) {
    size_t i = (size_t)blockIdx.x * 256 + threadIdx.x;  // float4 index
    int k4 = (int)(i & 63) * 4;
    float4 a = *(const float4*)(abuf + k4);
    float4 bb = *(const float4*)(bbuf + k4);
    float4 v = ((float4*)tok)[i];
    v.x = fmaxf(fmaf(a.x, v.x, bb.x), 0.f);
    v.y = fmaxf(fmaf(a.y, v.y, bb.y), 0.f);
    v.z = fmaxf(fmaf(a.z, v.z, bb.z), 0.f);
    v.w = fmaxf(fmaf(a.w, v.w, bb.w), 0.f);
    ((float4*)tok)[i] = v;
}

extern "C" void kernel_launch(void* const* d_in, const int* in_sizes, int n_in,
                              void* d_out, int out_size, void* d_ws, size_t ws_size,
                              hipStream_t stream) {
    const float* x        = (const float*)d_in[0];
    const float* loc      = (const float*)d_in[1];
    const int*   idx_agg  = (const int*)d_in[2];
    const float* aggw     = (const float*)d_in[3];
    const float* conv_w   = (const float*)d_in[4];
    const float* conv_b   = (const float*)d_in[5];
    const float* skip_w   = (const float*)d_in[6];
    const float* bn_gamma = (const float*)d_in[7];
    const float* bn_beta  = (const float*)d_in[8];
    const float* conf_w   = (const float*)d_in[9];
    const float* conf_b   = (const float*)d_in[10];

    float* ws      = (float*)d_ws;
    float* bnsum   = ws + BNSUM_OFF;
    float* bnsq    = ws + BNSQ_OFF;
    unsigned int* maxw = (unsigned int*)(ws + MAXW_OFF);
    int*   cnts    = (int*)(ws + CNTS_OFF);
    int*   curs    = (int*)(ws + CURS_OFF);
    unsigned short* ybuf  = (unsigned short*)(ws + YBUF_OFF);
    unsigned short* xmapn = (unsigned short*)(ws + XMAPN_OFF);
    unsigned short* xbf   = (unsigned short*)(ws + XBF_OFF);
    unsigned short* tokb  = (unsigned short*)(ws + TOKB_OFF);
    unsigned short* wfrag = (unsigned short*)(ws + WFRAG_OFF);
    unsigned short* sfrag = (unsigned short*)(ws + SFRAG_OFF);
    float* wexp    = ws + WEXP_OFF;
    float* awdt    = ws + AWDT_OFF;
    float* abuf    = ws + ABUF_OFF;
    float* bbuf    = ws + BBUF_OFF;
    float* cwa     = ws + CWA_OFF;
    float* c0      = ws + C0_OFF;
    int*   cell256 = (int*)(ws + CELL256_OFF);
    int*   cell64  = (int*)(ws + CELL64_OFF);
    float* den1    = ws + DEN1_OFF;
    float* den2    = ws + DEN2_OFF;
    int*   starts  = (int*)(ws + STARTS_OFF);
    int*   blksum  = (int*)(ws + BLKSUM_OFF);
    int*   blkexcl = (int*)(ws + BLKEXCL_OFF);
    int*   pidx    = (int*)(ws + PIDX_OFF);

    float* out       = (float*)d_out;
    float* out_xdown = out;                                    // [4,4096,256]
    float* out_x     = out + (size_t)BB * NS * COUT;           // [4,16384,256] (num -> tok -> relu(tokn))
    float* out_conf  = out_x + (size_t)BB * NTOK * COUT;       // [4,16384,1]
    float* out_awd   = out_conf + (size_t)BB * NTOK;           // [4,65536,1]
    float* out_idx   = out_awd + (size_t)BB * NP;              // [4,65536] written as float

    // zero the small accumulator region (ws is poisoned 0xAA every call)
    hipMemsetAsync(d_ws, 0, ZERO_FLOATS * sizeof(float), stream);

    k_cells<<<BB * NP / 256, 256, 0, stream>>>(loc, cell256, cell64);
    k_xcast<<<BB * NTOK * CIN / 4 / 256, 256, 0, stream>>>(x, xbf);
    k_wfrag<<<9 * 4 * 16 * 512 / 256, 256, 0, stream>>>(conv_w, wfrag);
    k_sfrag<<<4 * 16 * 512 / 256, 256, 0, stream>>>(skip_w, sfrag);
    k_hist<<<BB * NP / 256, 256, 0, stream>>>(cell256, idx_agg, cell64, cnts);
    k_scan1<<<NSEG / 1024, 256, 0, stream>>>(cnts, starts, blksum);
    k_scan2<<<1, 512, 0, stream>>>(blksum, blkexcl);
    k_fill<<<BB * NP / 256, 256, 0, stream>>>(cell256, idx_agg, cell64, starts,
                                              blkexcl, curs, pidx);
    k_gather_map<<<BB * NP / 8, 256, 0, stream>>>(xbf, starts, blkexcl, cnts, pidx, xmapn);
    k_convmf<<<BB * HD * 2, 256, 0, stream>>>(xmapn, wfrag, conv_b, ybuf);
    k_gather_tok<<<BB * NTOK / 4, 256, 0, stream>>>(ybuf, loc, aggw, starts, blkexcl,
                                                    cnts, pidx, out_x, den1);
    k_tokmf<<<BB * NTOK / 64, 256, 0, stream>>>(xbf, sfrag, den1, out_x);
    k_bnstats<<<BB * NTOK / 256, 256, 0, stream>>>(out_x, bnsum, bnsq);
    k_bnparams<<<1, 256, 0, stream>>>(bnsum, bnsq, bn_gamma, bn_beta, conf_w, conf_b,
                                      abuf, bbuf, cwa, c0);
    k_conf<<<BB * NTOK / 16, 256, 0, stream>>>(out_x, cwa, c0, abuf, bbuf,
                                               out_conf, tokb, wexp);
    k_gather_cluster<<<BB * NS / 4, 256, 0, stream>>>(tokb, wexp, starts, blkexcl,
                                                      cnts, pidx, out_xdown, den2);
    k_awd1<<<BB * 64, 256, 0, stream>>>(wexp, den2, idx_agg, cell64, aggw,
                                        awdt, out_idx, maxw);
    k_awd2<<<BB * NP / 256, 256, 0, stream>>>(awdt, maxw, out_awd);
    k_relutok<<<BB * NTOK * COUT / 4 / 256, 256, 0, stream>>>(out_x, abuf, bbuf);
}